// Round 12
// baseline (654.296 us; speedup 1.0000x reference)
//
#include <hip/hip_runtime.h>

#define DIN   128
#define DMID  256
#define DOUT  128
#define VNUM  50000

typedef __attribute__((ext_vector_type(8))) __bf16 bf16x8;
typedef __attribute__((ext_vector_type(4))) float  f32x4;

// ---- conversions (native HW cvt, RNE) ----
static __device__ __forceinline__ unsigned short b16(float f) {
  union { __bf16 b; unsigned short u; } r; r.b = (__bf16)f; return r.u;
}
static __device__ __forceinline__ unsigned pk2(float lo, float hi) {
  union { __bf16 b[2]; unsigned u; } r;
  r.b[0] = (__bf16)lo; r.b[1] = (__bf16)hi;
  return r.u;
}
// ---- order-preserving monotone maps ----
static __device__ __forceinline__ unsigned unflip_bits(unsigned m) {
  unsigned mask = ((int)m < 0) ? 0x80000000u : 0xFFFFFFFFu;
  return m ^ mask;
}
// flipped u16 -> flipped u32 of same bf16 widened to f32
static __device__ __forceinline__ unsigned flip32_from16(unsigned m) {
  return (m << 16) | ((m & 0x8000u) ? 0u : 0xFFFFu);
}

// ---------------------------------------------------------------------------
// Custom zero-fill. r11 lesson: the runtime's fillBufferAligned ran at
// 214 GB/s (240us for 51MB!) in this pipeline; a plain grid-stride uint4
// fill runs at multi-TB/s (~10-15us for the same region).
// ---------------------------------------------------------------------------
__global__ __launch_bounds__(256) void k_zero(uint4* __restrict__ p, int n16) {
  const int stride = gridDim.x * 256;
  const uint4 z = {0u, 0u, 0u, 0u};
  for (int i = blockIdx.x * 256 + threadIdx.x; i < n16; i += stride) p[i] = z;
}

// ---------------------------------------------------------------------------
// Sort machinery: hist -> multi-block scan -> PERMUTING COPY.
// r10 lesson: k1's wall was the random 512B x-row gather. The random access
// lives HERE now: barrier-free streaming kernel writes xs[p] = bf16(x[e])
// (scattered 256B stores, fire-and-forget) and svid[p]=v. k1 reads xs/svid
// CONTIGUOUSLY.
// ---------------------------------------------------------------------------
__global__ void k_hist(const int* __restrict__ vid, int* __restrict__ counts, int E) {
  int i = blockIdx.x * blockDim.x + threadIdx.x;
  if (i < E) atomicAdd(counts + vid[i], 1);
}

__global__ __launch_bounds__(256) void k_scan_red(
    const int* __restrict__ cnt, int* __restrict__ bsum, int V) {
  __shared__ int ws[4];
  const int i = blockIdx.x * 256 + threadIdx.x;
  int c = (i < V) ? cnt[i] : 0;
#pragma unroll
  for (int d = 1; d < 64; d <<= 1) c += __shfl_xor(c, d);
  if ((threadIdx.x & 63) == 0) ws[threadIdx.x >> 6] = c;
  __syncthreads();
  if (threadIdx.x == 0) bsum[blockIdx.x] = ws[0] + ws[1] + ws[2] + ws[3];
}

__global__ __launch_bounds__(256) void k_scan_top(int* __restrict__ bsum, int nb) {
  __shared__ int ws[4];
  const int tid = threadIdx.x, lane = tid & 63, wv = tid >> 6;
  int c = (tid < nb) ? bsum[tid] : 0;
  int s = c;
#pragma unroll
  for (int d = 1; d < 64; d <<= 1) {
    int u = __shfl_up(s, d, 64);
    if (lane >= d) s += u;
  }
  if (lane == 63) ws[wv] = s;
  __syncthreads();
  int off = 0;
  for (int k = 0; k < wv; ++k) off += ws[k];
  if (tid < nb) bsum[tid] = off + (s - c);
}

__global__ __launch_bounds__(256) void k_scan_fix(
    int* __restrict__ cursor, const int* __restrict__ bsum, int V) {
  __shared__ int ws[4];
  const int i = blockIdx.x * 256 + threadIdx.x;
  const int lane = threadIdx.x & 63, wv = threadIdx.x >> 6;
  int c = (i < V) ? cursor[i] : 0;
  int s = c;
#pragma unroll
  for (int d = 1; d < 64; d <<= 1) {
    int u = __shfl_up(s, d, 64);
    if (lane >= d) s += u;
  }
  if (lane == 63) ws[wv] = s;
  __syncthreads();
  int off = bsum[blockIdx.x];
  for (int k = 0; k < wv; ++k) off += ws[k];
  if (i < V) cursor[i] = off + (s - c);
}

// 8 threads per edge: leader atomicAdd's the vertex cursor, broadcasts p via
// shfl; group copies the 512B f32 row -> 256B bf16 row at xs[p], svid[p]=v.
__global__ __launch_bounds__(256) void k_scatter_copy(
    const float* __restrict__ x, const int* __restrict__ vid,
    int* __restrict__ cursor, unsigned short* __restrict__ xs,
    int* __restrict__ svid, int E) {
  const int g = blockIdx.x * 256 + threadIdx.x;
  const int e = g >> 3;
  if (e >= E) return;
  const int lane = threadIdx.x & 63;
  const int s8 = g & 7;
  const int v = vid[e];
  int p = 0;
  if (s8 == 0) p = atomicAdd(cursor + v, 1);
  p = __shfl(p, (lane >> 3) << 3, 64);   // broadcast from group leader

  const float4* src = reinterpret_cast<const float4*>(x + (size_t)e * DIN + s8 * 16);
  float4 a = src[0], b = src[1], c = src[2], d = src[3];
  uint4 o0 = { pk2(a.x, a.y), pk2(a.z, a.w), pk2(b.x, b.y), pk2(b.z, b.w) };
  uint4 o1 = { pk2(c.x, c.y), pk2(c.z, c.w), pk2(d.x, d.y), pk2(d.z, d.w) };
  uint4* dst = reinterpret_cast<uint4*>(xs + (size_t)p * DIN + s8 * 16);
  dst[0] = o0; dst[1] = o1;
  if (s8 == 0) svid[p] = v;
}

// ---------------------------------------------------------------------------
// Kernel 1: GEMM1 over PERMUTED xs (contiguous bf16 reads, no gather) +
// segmented max. r8 pipeline skeleton: 2 barriers/tile, next tile's rows
// prefetched to regs during phase 1, written to LDS after the walk.
// NOTE: NO min-waves hint (r5/r6: hints force spill-to-scratch).
// ---------------------------------------------------------------------------
__global__ __launch_bounds__(512) void k_gemm1_max(
    const unsigned short* __restrict__ xs, const int* __restrict__ svid,
    const float* __restrict__ W1, const float* __restrict__ b1,
    unsigned* __restrict__ zu, int ntiles) {
  __shared__ unsigned short lx[64 * 136];   // x tile bf16 (row-major)
  __shared__ unsigned short zt[256 * 70];   // z tile, flipped bf16, [col][row]
  __shared__ int lvid[2][64];

  const int tid  = threadIdx.x;
  const int lane = tid & 63;
  const int w    = tid >> 6;       // 0..7
  const int l15  = lane & 15;
  const int l4   = lane >> 4;
  const int row8 = tid >> 3;       // staging: 8 threads per row, 16 bf16 each
  const int s8   = tid & 7;
  const int G    = gridDim.x;

  // W1 fragments + bias for this wave's 32 cols
  bf16x8 bfrag[4][2];
  float  bias[2];
#pragma unroll
  for (int ni = 0; ni < 2; ++ni) {
    const int col = w * 32 + ni * 16 + l15;
    bias[ni] = b1[col];
#pragma unroll
    for (int kk = 0; kk < 4; ++kk) {
      union { bf16x8 v; unsigned short u[8]; } tmp;
#pragma unroll
      for (int j = 0; j < 8; ++j)
        tmp.u[j] = b16(W1[(kk * 32 + l4 * 8 + j) * DMID + col]);
      bfrag[kk][ni] = tmp.v;
    }
  }

  const int t0 = blockIdx.x;
  if (t0 >= ntiles) return;

  // ---- prologue: stage tile t0 ----
  {
    if (tid < 64) lvid[0][tid] = svid[t0 * 64 + tid];
    const uint4* s =
        reinterpret_cast<const uint4*>(xs + ((size_t)t0 * 64 + row8) * DIN + s8 * 16);
    uint4* dst = reinterpret_cast<uint4*>(&lx[row8 * 136 + s8 * 16]);
    dst[0] = s[0]; dst[1] = s[1];
  }
  __syncthreads();

  int cur = 0;
  for (int t = t0; t < ntiles; t += G, cur ^= 1) {
    const bool more = (t + G) < ntiles;

    // ---- phase 1: issue next tile's row + vid loads (contiguous) ----
    uint4 A0, A1; int vN = 0;
    if (more) {
      const uint4* s = reinterpret_cast<const uint4*>(
          xs + ((size_t)(t + G) * 64 + row8) * DIN + s8 * 16);
      A0 = s[0]; A1 = s[1];
      if (tid < 64) vN = svid[(t + G) * 64 + tid];
    }

    // uniform run-end mask (bit r = row r ends a vid run)
    const int myv = lvid[cur][lane];
    const int nv  = (lane == 63) ? (myv ^ 1) : lvid[cur][lane + 1];
    const unsigned long long emask = __ballot(myv != nv);
    const bool contOpen = (lvid[cur][31] == lvid[cur][32]);

    // ---- MFMA: 64 rows x 32 cols per wave, K=128 ----
    f32x4 acc[4][2];
#pragma unroll
    for (int mi = 0; mi < 4; ++mi)
#pragma unroll
      for (int ni = 0; ni < 2; ++ni)
        acc[mi][ni] = (f32x4){bias[ni], bias[ni], bias[ni], bias[ni]};
#pragma unroll
    for (int kk = 0; kk < 4; ++kk) {
      bf16x8 a[4];
#pragma unroll
      for (int mi = 0; mi < 4; ++mi)
        a[mi] = *reinterpret_cast<const bf16x8*>(
            &lx[(mi * 16 + l15) * 136 + kk * 32 + l4 * 8]);
#pragma unroll
      for (int mi = 0; mi < 4; ++mi)
#pragma unroll
        for (int ni = 0; ni < 2; ++ni)
          acc[mi][ni] = __builtin_amdgcn_mfma_f32_16x16x32_bf16(
              a[mi], bfrag[kk][ni], acc[mi][ni], 0, 0, 0);
    }

    // ---- pack acc -> zt (flipped bf16, column-major) ----
    {
      unsigned* ztw = reinterpret_cast<unsigned*>(zt);
#pragma unroll
      for (int ni = 0; ni < 2; ++ni) {
        const int col = w * 32 + ni * 16 + l15;
        const int cb  = col * 35 + l4 * 2;
#pragma unroll
        for (int mi = 0; mi < 4; ++mi)
#pragma unroll
          for (int p = 0; p < 2; ++p) {
            unsigned tpk = pk2(acc[mi][ni][2 * p], acc[mi][ni][2 * p + 1]);
            unsigned mflip = 0x80008000u + ((tpk >> 15) & 0x00010001u) * 0x7FFFu;
            ztw[cb + mi * 8 + p] = tpk ^ mflip;
          }
      }
    }
    __syncthreads();   // zt visible; lx consumed

    // ---- walk zt(t): 2 threads per column, 32 rows each ----
    {
      const int col = tid & 255;
      const int h   = tid >> 8;
      const unsigned* zc = reinterpret_cast<const unsigned*>(&zt[col * 70 + h * 32]);
      unsigned curm = 0;
      bool first = true;
#pragma unroll
      for (int p = 0; p < 16; ++p) {
        const unsigned pr = zc[p];
#pragma unroll
        for (int j = 0; j < 2; ++j) {
          const unsigned val = j ? (pr >> 16) : (pr & 0xFFFFu);
          curm = val > curm ? val : curm;
          const int row = h * 32 + p * 2 + j;
          if ((emask >> row) & 1) {
            const int v = lvid[cur][row];
            const unsigned enc = flip32_from16(curm);
            unsigned* ad = zu + (size_t)v * DMID + col;
            if (row == 63 || (first && (h == 0 || contOpen))) atomicMax(ad, enc);
            else *ad = enc;
            curm = 0; first = false;
          }
        }
      }
      if (h == 0 && !((emask >> 31) & 1)) {  // trailing open run in top half
        const int v = lvid[cur][31];
        atomicMax(zu + (size_t)v * DMID + col, flip32_from16(curm));
      }
    }

    // ---- write prefetched tile to LDS ----
    if (more) {
      uint4* dst = reinterpret_cast<uint4*>(&lx[row8 * 136 + s8 * 16]);
      dst[0] = A0; dst[1] = A1;
      if (tid < 64) lvid[cur ^ 1][tid] = vN;
    }
    __syncthreads();   // stage visible; walk complete before next pack
  }
}

// ---------------------------------------------------------------------------
// Kernel Y: Y = unflip(zu) @ W2b  (V x 128). Block 256, wave 2x2.
// ---------------------------------------------------------------------------
__global__ __launch_bounds__(256) void k_ymm(
    const unsigned* __restrict__ zu, const float* __restrict__ W2,
    float* __restrict__ Y, int ntiles) {
  extern __shared__ unsigned short sm[];
  unsigned short* w2bt = sm;               // [128][264]
  unsigned short* za   = sm + 128 * 264;   // [64][264]

  const int tid  = threadIdx.x;
  const int lane = tid & 63;
  const int w    = tid >> 6;
  const int wr   = w >> 1, wc = w & 1;
  const int l15  = lane & 15, l4 = lane >> 4;

  {
    const int n = tid & 127, kh = tid >> 7;
    for (int k = kh * 128; k < kh * 128 + 128; ++k)
      w2bt[n * 264 + k] = b16(W2[(size_t)(DIN + k) * DOUT + n]);
  }
  __syncthreads();

  for (int t = blockIdx.x; t < ntiles; t += gridDim.x) {
    {
      const int row = tid >> 2, q = tid & 3;
      const int v = t * 64 + row;
      unsigned short* dz = &za[row * 264 + q * 64];
      if (v < VNUM) {
        const uint4* sz = reinterpret_cast<const uint4*>(zu + (size_t)v * DMID + q * 64);
#pragma unroll
        for (int i = 0; i < 16; ++i) {
          uint4 m = sz[i];
          ushort4 o = { (unsigned short)(unflip_bits(m.x) >> 16),
                        (unsigned short)(unflip_bits(m.y) >> 16),
                        (unsigned short)(unflip_bits(m.z) >> 16),
                        (unsigned short)(unflip_bits(m.w) >> 16) };
          *reinterpret_cast<ushort4*>(dz + i * 4) = o;
        }
      } else {
        ushort4 zo = {0, 0, 0, 0};
#pragma unroll
        for (int i = 0; i < 16; ++i) *reinterpret_cast<ushort4*>(dz + i * 4) = zo;
      }
    }
    __syncthreads();

    f32x4 acc[2][4];
#pragma unroll
    for (int mi = 0; mi < 2; ++mi)
#pragma unroll
      for (int ni = 0; ni < 4; ++ni) acc[mi][ni] = (f32x4){0.f, 0.f, 0.f, 0.f};

#pragma unroll
    for (int kk = 0; kk < 8; ++kk) {
      bf16x8 a[2], b[4];
#pragma unroll
      for (int mi = 0; mi < 2; ++mi)
        a[mi] = *reinterpret_cast<const bf16x8*>(
            &za[(wr * 32 + mi * 16 + l15) * 264 + kk * 32 + l4 * 8]);
#pragma unroll
      for (int ni = 0; ni < 4; ++ni)
        b[ni] = *reinterpret_cast<const bf16x8*>(
            &w2bt[(wc * 64 + ni * 16 + l15) * 264 + kk * 32 + l4 * 8]);
#pragma unroll
      for (int mi = 0; mi < 2; ++mi)
#pragma unroll
        for (int ni = 0; ni < 4; ++ni)
          acc[mi][ni] = __builtin_amdgcn_mfma_f32_16x16x32_bf16(
              a[mi], b[ni], acc[mi][ni], 0, 0, 0);
    }

#pragma unroll
    for (int mi = 0; mi < 2; ++mi)
#pragma unroll
      for (int r = 0; r < 4; ++r) {
        const int v = t * 64 + wr * 32 + mi * 16 + l4 * 4 + r;
        if (v < VNUM) {
          float* o = Y + (size_t)v * DOUT + wc * 64 + l15;
#pragma unroll
          for (int ni = 0; ni < 4; ++ni) o[ni * 16] = acc[mi][ni][r];
        }
      }
    __syncthreads();
  }
}

// ---------------------------------------------------------------------------
// Kernel 2: out = x @ W2a + Y[vid]  (original edge order). Block 256, wave 2x2.
// ---------------------------------------------------------------------------
__global__ __launch_bounds__(256, 3) void k_gemm2(
    const float* __restrict__ x, const int* __restrict__ vid,
    const float* __restrict__ W2, const float* __restrict__ Y,
    float* __restrict__ out, int ntiles) {
  __shared__ unsigned short w2at[128 * 136];
  __shared__ unsigned short lx[64 * 136];
  __shared__ int lvid[64];

  const int tid  = threadIdx.x;
  const int lane = tid & 63;
  const int w    = tid >> 6;
  const int wr   = w >> 1, wc = w & 1;
  const int l15  = lane & 15, l4 = lane >> 4;

  {
    const int n = tid & 127, kh = tid >> 7;
    for (int k = kh * 64; k < kh * 64 + 64; ++k)
      w2at[n * 136 + k] = b16(W2[(size_t)k * DOUT + n]);
  }
  __syncthreads();

  for (int t = blockIdx.x; t < ntiles; t += gridDim.x) {
    {
      const int row = tid >> 2, q = tid & 3;
      const float4* sx =
          reinterpret_cast<const float4*>(x + (size_t)(t * 64 + row) * DIN + q * 32);
#pragma unroll
      for (int i = 0; i < 8; ++i) {
        float4 v = sx[i];
        uint2 o = { pk2(v.x, v.y), pk2(v.z, v.w) };
        *reinterpret_cast<uint2*>(&lx[row * 136 + q * 32 + i * 4]) = o;
      }
      if (tid < 64) lvid[tid] = vid[t * 64 + tid];
    }
    __syncthreads();

    f32x4 acc[2][4];
#pragma unroll
    for (int mi = 0; mi < 2; ++mi)
#pragma unroll
      for (int ni = 0; ni < 4; ++ni) acc[mi][ni] = (f32x4){0.f, 0.f, 0.f, 0.f};

#pragma unroll
    for (int kk = 0; kk < 4; ++kk) {
      bf16x8 a[2], b[4];
#pragma unroll
      for (int mi = 0; mi < 2; ++mi)
        a[mi] = *reinterpret_cast<const bf16x8*>(
            &lx[(wr * 32 + mi * 16 + l15) * 136 + kk * 32 + l4 * 8]);
#pragma unroll
      for (int ni = 0; ni < 4; ++ni)
        b[ni] = *reinterpret_cast<const bf16x8*>(
            &w2at[(wc * 64 + ni * 16 + l15) * 136 + kk * 32 + l4 * 8]);
#pragma unroll
      for (int mi = 0; mi < 2; ++mi)
#pragma unroll
        for (int ni = 0; ni < 4; ++ni)
          acc[mi][ni] = __builtin_amdgcn_mfma_f32_16x16x32_bf16(
              a[mi], b[ni], acc[mi][ni], 0, 0, 0);
    }

    // epilogue: + Y[vid], fp32 store
#pragma unroll
    for (int mi = 0; mi < 2; ++mi)
#pragma unroll
      for (int r = 0; r < 4; ++r) {
        const int row = wr * 32 + mi * 16 + l4 * 4 + r;
        const float* Yr = Y + (size_t)lvid[row] * DOUT + wc * 64 + l15;
        float* o = out + (size_t)(t * 64 + row) * DOUT + wc * 64 + l15;
#pragma unroll
        for (int ni = 0; ni < 4; ++ni) o[ni * 16] = acc[mi][ni][r] + Yr[ni * 16];
      }
    __syncthreads();
  }
}

// ---------------------------------------------------------------------------
extern "C" void kernel_launch(void* const* d_in, const int* in_sizes, int n_in,
                              void* d_out, int out_size, void* d_ws, size_t ws_size,
                              hipStream_t stream) {
  const float* x   = (const float*)d_in[0];
  const int*   vid = (const int*)d_in[1];
  const float* W1  = (const float*)d_in[2];
  const float* b1  = (const float*)d_in[3];
  const float* W2  = (const float*)d_in[4];
  float* out = (float*)d_out;

  const int E = in_sizes[1];      // 800000 (divisible by 64)
  const int ntiles = E / 64;
  const int ntY = (VNUM + 63) / 64;   // 782
  const int nb = (VNUM + 255) / 256;  // 196 scan blocks

  char* ws = (char*)d_ws;
  size_t off = 0;
  unsigned* zu = (unsigned*)(ws + off); off += (size_t)VNUM * DMID * 4;
  int* cnt     = (int*)(ws + off);      off += (size_t)VNUM * 4;
  float* Y     = (float*)(ws + off);    off += (size_t)VNUM * DOUT * 4;
  int* bsum    = (int*)(ws + off);      off += 4096;
  int* svid    = (int*)(ws + off);      off += (size_t)E * 4;
  unsigned short* xs = (unsigned short*)(ws + off);  // E*128 bf16 = 204.8MB

  // zero zu + cnt (contiguous, 51.4MB) with our own fill — the runtime's
  // fillBufferAligned ran at 214 GB/s here (240us/iter, r11 top dispatch).
  const int n16 = (int)(((size_t)VNUM * DMID * 4 + VNUM * 4) / 16);
  k_zero<<<2048, 256, 0, stream>>>((uint4*)zu, n16);

  k_hist<<<(E + 255) / 256, 256, 0, stream>>>(vid, cnt, E);
  k_scan_red<<<nb, 256, 0, stream>>>(cnt, bsum, VNUM);
  k_scan_top<<<1, 256, 0, stream>>>(bsum, nb);
  k_scan_fix<<<nb, 256, 0, stream>>>(cnt, bsum, VNUM);
  // permuting copy: x (f32, original order) -> xs (bf16, vertex-sorted)
  k_scatter_copy<<<(E * 8 + 255) / 256, 256, 0, stream>>>(x, vid, cnt, xs, svid, E);

  k_gemm1_max<<<2048, 512, 0, stream>>>(xs, svid, W1, b1, zu, ntiles);

  const int smY = (128 * 264 + 64 * 264) * sizeof(unsigned short);
  hipFuncSetAttribute((const void*)k_ymm,
                      hipFuncAttributeMaxDynamicSharedMemorySize, smY);
  k_ymm<<<782, 256, smY, stream>>>(zu, W2, Y, ntY);

  k_gemm2<<<768, 256, 0, stream>>>(x, vid, W2, Y, out, ntiles);
}

// Round 13
// 623.815 us; speedup vs baseline: 1.0489x; 1.0489x over previous
//
#include <hip/hip_runtime.h>

#define DIN   128
#define DMID  256
#define DOUT  128
#define VNUM  50000

typedef __attribute__((ext_vector_type(8))) __bf16 bf16x8;
typedef __attribute__((ext_vector_type(4))) float  f32x4;

// ---- conversions (native HW cvt, RNE) ----
static __device__ __forceinline__ unsigned short b16(float f) {
  union { __bf16 b; unsigned short u; } r; r.b = (__bf16)f; return r.u;
}
static __device__ __forceinline__ unsigned pk2(float lo, float hi) {
  union { __bf16 b[2]; unsigned u; } r;
  r.b[0] = (__bf16)lo; r.b[1] = (__bf16)hi;
  return r.u;
}
// ---- order-preserving monotone maps ----
static __device__ __forceinline__ unsigned unflip_bits(unsigned m) {
  unsigned mask = ((int)m < 0) ? 0x80000000u : 0xFFFFFFFFu;
  return m ^ mask;
}
// flipped u16 -> flipped u32 of same bf16 widened to f32
static __device__ __forceinline__ unsigned flip32_from16(unsigned m) {
  return (m << 16) | ((m & 0x8000u) ? 0u : 0xFFFFu);
}

// ---------------------------------------------------------------------------
// Custom zero-fill of zu+cnt (51.4MB).
// ---------------------------------------------------------------------------
__global__ __launch_bounds__(256) void k_zero(uint4* __restrict__ p, int n16) {
  const int stride = gridDim.x * 256;
  const uint4 z = {0u, 0u, 0u, 0u};
  for (int i = blockIdx.x * 256 + threadIdx.x; i < n16; i += stride) p[i] = z;
}

// ---------------------------------------------------------------------------
// Sort machinery: hist -> multi-block scan -> index scatter.
// (r12 lesson: the permuting-copy variant cost MORE than gather-k1 saved —
// r8 total 608 vs r12 654. Index-only scatter + gather-k1 is the best
// measured configuration.)
// ---------------------------------------------------------------------------
__global__ void k_hist(const int* __restrict__ vid, int* __restrict__ counts, int E) {
  int i = blockIdx.x * blockDim.x + threadIdx.x;
  if (i < E) atomicAdd(counts + vid[i], 1);
}

__global__ __launch_bounds__(256) void k_scan_red(
    const int* __restrict__ cnt, int* __restrict__ bsum, int V) {
  __shared__ int ws[4];
  const int i = blockIdx.x * 256 + threadIdx.x;
  int c = (i < V) ? cnt[i] : 0;
#pragma unroll
  for (int d = 1; d < 64; d <<= 1) c += __shfl_xor(c, d);
  if ((threadIdx.x & 63) == 0) ws[threadIdx.x >> 6] = c;
  __syncthreads();
  if (threadIdx.x == 0) bsum[blockIdx.x] = ws[0] + ws[1] + ws[2] + ws[3];
}

__global__ __launch_bounds__(256) void k_scan_top(int* __restrict__ bsum, int nb) {
  __shared__ int ws[4];
  const int tid = threadIdx.x, lane = tid & 63, wv = tid >> 6;
  int c = (tid < nb) ? bsum[tid] : 0;
  int s = c;
#pragma unroll
  for (int d = 1; d < 64; d <<= 1) {
    int u = __shfl_up(s, d, 64);
    if (lane >= d) s += u;
  }
  if (lane == 63) ws[wv] = s;
  __syncthreads();
  int off = 0;
  for (int k = 0; k < wv; ++k) off += ws[k];
  if (tid < nb) bsum[tid] = off + (s - c);
}

__global__ __launch_bounds__(256) void k_scan_fix(
    int* __restrict__ cursor, const int* __restrict__ bsum, int V) {
  __shared__ int ws[4];
  const int i = blockIdx.x * 256 + threadIdx.x;
  const int lane = threadIdx.x & 63, wv = threadIdx.x >> 6;
  int c = (i < V) ? cursor[i] : 0;
  int s = c;
#pragma unroll
  for (int d = 1; d < 64; d <<= 1) {
    int u = __shfl_up(s, d, 64);
    if (lane >= d) s += u;
  }
  if (lane == 63) ws[wv] = s;
  __syncthreads();
  int off = bsum[blockIdx.x];
  for (int k = 0; k < wv; ++k) off += ws[k];
  if (i < V) cursor[i] = off + (s - c);
}

__global__ void k_scatter(const int* __restrict__ vid, int* __restrict__ cursor,
                          int* __restrict__ sorted, int E) {
  int i = blockIdx.x * blockDim.x + threadIdx.x;
  if (i < E) {
    int v = vid[i];
    int p = atomicAdd(cursor + v, 1);
    sorted[p] = i;
  }
}

// ---------------------------------------------------------------------------
// Kernel 1: GEMM1 over sorted edges; 2 barriers/tile, software-pipelined:
//   [emask; MFMA; pack->zt] bar [issue next-tile loads; walk zt->zu; cvt+write]
// bar. (r8 configuration — best measured.)
// NOTE: NO min-waves hint in __launch_bounds__ — peak live set ~120 VGPR;
// hints of 4/6 squeezed the allocator to 64/40 VGPR and spilled to scratch
// every tile (r5/r6: FETCH 0.9-1.3GB vs 430MB ideal).
// ---------------------------------------------------------------------------
__global__ __launch_bounds__(512) void k_gemm1_max(
    const float* __restrict__ x, const int* __restrict__ vid,
    const int* __restrict__ sorted, const float* __restrict__ W1,
    const float* __restrict__ b1, unsigned* __restrict__ zu, int ntiles) {
  __shared__ unsigned short lx[64 * 136];   // x tile bf16 (row-major)
  __shared__ unsigned short zt[256 * 70];   // z tile, flipped bf16, [col][row]
  __shared__ int lvid[2][64];

  const int tid  = threadIdx.x;
  const int lane = tid & 63;
  const int w    = tid >> 6;       // 0..7
  const int l15  = lane & 15;
  const int l4   = lane >> 4;
  const int row8 = tid >> 3;       // staging: 8 threads per row
  const int s8   = tid & 7;        // 16 floats each
  const int G    = gridDim.x;

  // W1 fragments + bias for this wave's 32 cols
  bf16x8 bfrag[4][2];
  float  bias[2];
#pragma unroll
  for (int ni = 0; ni < 2; ++ni) {
    const int col = w * 32 + ni * 16 + l15;
    bias[ni] = b1[col];
#pragma unroll
    for (int kk = 0; kk < 4; ++kk) {
      union { bf16x8 v; unsigned short u[8]; } tmp;
#pragma unroll
      for (int j = 0; j < 8; ++j)
        tmp.u[j] = b16(W1[(kk * 32 + l4 * 8 + j) * DMID + col]);
      bfrag[kk][ni] = tmp.v;
    }
  }

  const int t0 = blockIdx.x;
  if (t0 >= ntiles) return;

  // ---- prologue: stage tile t0 ----
  {
    if (tid < 64) lvid[0][tid] = vid[sorted[t0 * 64 + tid]];
    const int eid = sorted[t0 * 64 + row8];
    const float4* src =
        reinterpret_cast<const float4*>(x + (size_t)eid * DIN + s8 * 16);
#pragma unroll
    for (int i = 0; i < 4; ++i) {
      float4 v = src[i];
      uint2 o = { pk2(v.x, v.y), pk2(v.z, v.w) };
      *reinterpret_cast<uint2*>(&lx[row8 * 136 + s8 * 16 + i * 4]) = o;
    }
  }
  __syncthreads();

  int cur = 0;
  for (int t = t0; t < ntiles; t += G, cur ^= 1) {
    const int tn = t + G;
    const bool more = (tn < ntiles);
    // issue next-tile index loads early (covered by MFMA+pack)
    int eidN = 0, sidN = 0;
    if (more) {
      eidN = sorted[tn * 64 + row8];
      if (tid < 64) sidN = sorted[tn * 64 + tid];
    }

    // uniform run-end mask (bit r = row r ends a vid run)
    const int myv = lvid[cur][lane];
    const int nv  = (lane == 63) ? (myv ^ 1) : lvid[cur][lane + 1];
    const unsigned long long emask = __ballot(myv != nv);
    const bool contOpen = (lvid[cur][31] == lvid[cur][32]);

    // ---- MFMA: 64 rows x 32 cols per wave, K=128 ----
    f32x4 acc[4][2];
#pragma unroll
    for (int mi = 0; mi < 4; ++mi)
#pragma unroll
      for (int ni = 0; ni < 2; ++ni)
        acc[mi][ni] = (f32x4){bias[ni], bias[ni], bias[ni], bias[ni]};
#pragma unroll
    for (int kk = 0; kk < 4; ++kk) {
      bf16x8 a[4];
#pragma unroll
      for (int mi = 0; mi < 4; ++mi)
        a[mi] = *reinterpret_cast<const bf16x8*>(
            &lx[(mi * 16 + l15) * 136 + kk * 32 + l4 * 8]);
#pragma unroll
      for (int mi = 0; mi < 4; ++mi)
#pragma unroll
        for (int ni = 0; ni < 2; ++ni)
          acc[mi][ni] = __builtin_amdgcn_mfma_f32_16x16x32_bf16(
              a[mi], bfrag[kk][ni], acc[mi][ni], 0, 0, 0);
    }

    // ---- pack acc -> zt (flipped bf16, column-major) ----
    {
      unsigned* ztw = reinterpret_cast<unsigned*>(zt);
#pragma unroll
      for (int ni = 0; ni < 2; ++ni) {
        const int col = w * 32 + ni * 16 + l15;
        const int cb  = col * 35 + l4 * 2;
#pragma unroll
        for (int mi = 0; mi < 4; ++mi)
#pragma unroll
          for (int p = 0; p < 2; ++p) {
            unsigned tpk = pk2(acc[mi][ni][2 * p], acc[mi][ni][2 * p + 1]);
            unsigned mflip = 0x80008000u + ((tpk >> 15) & 0x00010001u) * 0x7FFFu;
            ztw[cb + mi * 8 + p] = tpk ^ mflip;
          }
      }
    }
    __syncthreads();   // zt visible; lx consumed

    // ---- issue next tile's x + vid loads (latency hidden by walk) ----
    float4 x0, x1, x2, x3;
    int vN = 0;
    if (more) {
      const float4* src =
          reinterpret_cast<const float4*>(x + (size_t)eidN * DIN + s8 * 16);
      x0 = src[0]; x1 = src[1]; x2 = src[2]; x3 = src[3];
      if (tid < 64) vN = vid[sidN];
    }

    // ---- walk zt(t): 2 threads per column, 32 rows each ----
    {
      const int col = tid & 255;
      const int h   = tid >> 8;
      const unsigned* zc = reinterpret_cast<const unsigned*>(&zt[col * 70 + h * 32]);
      unsigned curm = 0;
      bool first = true;
#pragma unroll
      for (int p = 0; p < 16; ++p) {
        const unsigned pr = zc[p];
#pragma unroll
        for (int j = 0; j < 2; ++j) {
          const unsigned val = j ? (pr >> 16) : (pr & 0xFFFFu);
          curm = val > curm ? val : curm;
          const int row = h * 32 + p * 2 + j;
          if ((emask >> row) & 1) {
            const int v = lvid[cur][row];
            const unsigned enc = flip32_from16(curm);
            unsigned* ad = zu + (size_t)v * DMID + col;
            if (row == 63 || (first && (h == 0 || contOpen))) atomicMax(ad, enc);
            else *ad = enc;
            curm = 0; first = false;
          }
        }
      }
      if (h == 0 && !((emask >> 31) & 1)) {  // trailing open run in top half
        const int v = lvid[cur][31];
        atomicMax(zu + (size_t)v * DMID + col, flip32_from16(curm));
      }
    }

    // ---- convert + write next tile to LDS ----
    if (more) {
      uint2 o0 = { pk2(x0.x, x0.y), pk2(x0.z, x0.w) };
      uint2 o1 = { pk2(x1.x, x1.y), pk2(x1.z, x1.w) };
      uint2 o2 = { pk2(x2.x, x2.y), pk2(x2.z, x2.w) };
      uint2 o3 = { pk2(x3.x, x3.y), pk2(x3.z, x3.w) };
      unsigned short* dst = &lx[row8 * 136 + s8 * 16];
      *reinterpret_cast<uint2*>(dst + 0)  = o0;
      *reinterpret_cast<uint2*>(dst + 4)  = o1;
      *reinterpret_cast<uint2*>(dst + 8)  = o2;
      *reinterpret_cast<uint2*>(dst + 12) = o3;
      if (tid < 64) lvid[cur ^ 1][tid] = vN;
    }
    __syncthreads();   // stage visible; walk complete before next pack
  }
}

// ---------------------------------------------------------------------------
// Kernel Y: Y = unflip(zu) @ W2b  (V x 128). Block 256, wave 2x2.
// ---------------------------------------------------------------------------
__global__ __launch_bounds__(256) void k_ymm(
    const unsigned* __restrict__ zu, const float* __restrict__ W2,
    float* __restrict__ Y, int ntiles) {
  extern __shared__ unsigned short sm[];
  unsigned short* w2bt = sm;               // [128][264]
  unsigned short* za   = sm + 128 * 264;   // [64][264]

  const int tid  = threadIdx.x;
  const int lane = tid & 63;
  const int w    = tid >> 6;
  const int wr   = w >> 1, wc = w & 1;
  const int l15  = lane & 15, l4 = lane >> 4;

  {
    const int n = tid & 127, kh = tid >> 7;
    for (int k = kh * 128; k < kh * 128 + 128; ++k)
      w2bt[n * 264 + k] = b16(W2[(size_t)(DIN + k) * DOUT + n]);
  }
  __syncthreads();

  for (int t = blockIdx.x; t < ntiles; t += gridDim.x) {
    {
      const int row = tid >> 2, q = tid & 3;
      const int v = t * 64 + row;
      unsigned short* dz = &za[row * 264 + q * 64];
      if (v < VNUM) {
        const uint4* sz = reinterpret_cast<const uint4*>(zu + (size_t)v * DMID + q * 64);
#pragma unroll
        for (int i = 0; i < 16; ++i) {
          uint4 m = sz[i];
          ushort4 o = { (unsigned short)(unflip_bits(m.x) >> 16),
                        (unsigned short)(unflip_bits(m.y) >> 16),
                        (unsigned short)(unflip_bits(m.z) >> 16),
                        (unsigned short)(unflip_bits(m.w) >> 16) };
          *reinterpret_cast<ushort4*>(dz + i * 4) = o;
        }
      } else {
        ushort4 zo = {0, 0, 0, 0};
#pragma unroll
        for (int i = 0; i < 16; ++i) *reinterpret_cast<ushort4*>(dz + i * 4) = zo;
      }
    }
    __syncthreads();

    f32x4 acc[2][4];
#pragma unroll
    for (int mi = 0; mi < 2; ++mi)
#pragma unroll
      for (int ni = 0; ni < 4; ++ni) acc[mi][ni] = (f32x4){0.f, 0.f, 0.f, 0.f};

#pragma unroll
    for (int kk = 0; kk < 8; ++kk) {
      bf16x8 a[2], b[4];
#pragma unroll
      for (int mi = 0; mi < 2; ++mi)
        a[mi] = *reinterpret_cast<const bf16x8*>(
            &za[(wr * 32 + mi * 16 + l15) * 264 + kk * 32 + l4 * 8]);
#pragma unroll
      for (int ni = 0; ni < 4; ++ni)
        b[ni] = *reinterpret_cast<const bf16x8*>(
            &w2bt[(wc * 64 + ni * 16 + l15) * 264 + kk * 32 + l4 * 8]);
#pragma unroll
      for (int mi = 0; mi < 2; ++mi)
#pragma unroll
        for (int ni = 0; ni < 4; ++ni)
          acc[mi][ni] = __builtin_amdgcn_mfma_f32_16x16x32_bf16(
              a[mi], b[ni], acc[mi][ni], 0, 0, 0);
    }

#pragma unroll
    for (int mi = 0; mi < 2; ++mi)
#pragma unroll
      for (int r = 0; r < 4; ++r) {
        const int v = t * 64 + wr * 32 + mi * 16 + l4 * 4 + r;
        if (v < VNUM) {
          float* o = Y + (size_t)v * DOUT + wc * 64 + l15;
#pragma unroll
          for (int ni = 0; ni < 4; ++ni) o[ni * 16] = acc[mi][ni][r];
        }
      }
    __syncthreads();
  }
}

// ---------------------------------------------------------------------------
// Kernel 2: out = x @ W2a + Y[vid]  (original edge order). Block 256, wave
// 2x2. NEW: Y[vid] gathers issued EARLY (right after the staging barrier,
// before MFMA) so their L3 latency hides under the MFMA+LDS work — the old
// epilogue-gather exposed ~32 random-row latencies per tile, serialized
// before the stores.
// ---------------------------------------------------------------------------
__global__ __launch_bounds__(256, 3) void k_gemm2(
    const float* __restrict__ x, const int* __restrict__ vid,
    const float* __restrict__ W2, const float* __restrict__ Y,
    float* __restrict__ out, int ntiles) {
  __shared__ unsigned short w2at[128 * 136];
  __shared__ unsigned short lx[64 * 136];
  __shared__ int lvid[64];

  const int tid  = threadIdx.x;
  const int lane = tid & 63;
  const int w    = tid >> 6;
  const int wr   = w >> 1, wc = w & 1;
  const int l15  = lane & 15, l4 = lane >> 4;

  {
    const int n = tid & 127, kh = tid >> 7;
    for (int k = kh * 64; k < kh * 64 + 64; ++k)
      w2at[n * 136 + k] = b16(W2[(size_t)k * DOUT + n]);
  }
  __syncthreads();

  for (int t = blockIdx.x; t < ntiles; t += gridDim.x) {
    {
      const int row = tid >> 2, q = tid & 3;
      const float4* sx =
          reinterpret_cast<const float4*>(x + (size_t)(t * 64 + row) * DIN + q * 32);
#pragma unroll
      for (int i = 0; i < 8; ++i) {
        float4 v = sx[i];
        uint2 o = { pk2(v.x, v.y), pk2(v.z, v.w) };
        *reinterpret_cast<uint2*>(&lx[row * 136 + q * 32 + i * 4]) = o;
      }
      if (tid < 64) lvid[tid] = vid[t * 64 + tid];
    }
    __syncthreads();

    // ---- issue Y gathers for this tile (consumed after MFMA) ----
    float yv[2][4][4];  // [mi][r][ni]
#pragma unroll
    for (int mi = 0; mi < 2; ++mi)
#pragma unroll
      for (int r = 0; r < 4; ++r) {
        const int row = wr * 32 + mi * 16 + l4 * 4 + r;
        const float* Yr = Y + (size_t)lvid[row] * DOUT + wc * 64 + l15;
#pragma unroll
        for (int ni = 0; ni < 4; ++ni) yv[mi][r][ni] = Yr[ni * 16];
      }

    f32x4 acc[2][4];
#pragma unroll
    for (int mi = 0; mi < 2; ++mi)
#pragma unroll
      for (int ni = 0; ni < 4; ++ni) acc[mi][ni] = (f32x4){0.f, 0.f, 0.f, 0.f};

#pragma unroll
    for (int kk = 0; kk < 4; ++kk) {
      bf16x8 a[2], b[4];
#pragma unroll
      for (int mi = 0; mi < 2; ++mi)
        a[mi] = *reinterpret_cast<const bf16x8*>(
            &lx[(wr * 32 + mi * 16 + l15) * 136 + kk * 32 + l4 * 8]);
#pragma unroll
      for (int ni = 0; ni < 4; ++ni)
        b[ni] = *reinterpret_cast<const bf16x8*>(
            &w2at[(wc * 64 + ni * 16 + l15) * 136 + kk * 32 + l4 * 8]);
#pragma unroll
      for (int mi = 0; mi < 2; ++mi)
#pragma unroll
        for (int ni = 0; ni < 4; ++ni)
          acc[mi][ni] = __builtin_amdgcn_mfma_f32_16x16x32_bf16(
              a[mi], b[ni], acc[mi][ni], 0, 0, 0);
    }

    // epilogue: + Y (prefetched), fp32 store
#pragma unroll
    for (int mi = 0; mi < 2; ++mi)
#pragma unroll
      for (int r = 0; r < 4; ++r) {
        const int row = wr * 32 + mi * 16 + l4 * 4 + r;
        float* o = out + (size_t)(t * 64 + row) * DOUT + wc * 64 + l15;
#pragma unroll
        for (int ni = 0; ni < 4; ++ni) o[ni * 16] = acc[mi][ni][r] + yv[mi][r][ni];
      }
    __syncthreads();
  }
}

// ---------------------------------------------------------------------------
extern "C" void kernel_launch(void* const* d_in, const int* in_sizes, int n_in,
                              void* d_out, int out_size, void* d_ws, size_t ws_size,
                              hipStream_t stream) {
  const float* x   = (const float*)d_in[0];
  const int*   vid = (const int*)d_in[1];
  const float* W1  = (const float*)d_in[2];
  const float* b1  = (const float*)d_in[3];
  const float* W2  = (const float*)d_in[4];
  float* out = (float*)d_out;

  const int E = in_sizes[1];      // 800000 (divisible by 64)
  const int ntiles = E / 64;
  const int ntY = (VNUM + 63) / 64;   // 782
  const int nb = (VNUM + 255) / 256;  // 196 scan blocks

  char* ws = (char*)d_ws;
  size_t off = 0;
  unsigned* zu = (unsigned*)(ws + off); off += (size_t)VNUM * DMID * 4;
  int* cnt     = (int*)(ws + off);      off += (size_t)VNUM * 4;
  int* sorted  = (int*)(ws + off);      off += (size_t)E * 4;
  float* Y     = (float*)(ws + off);    off += (size_t)VNUM * DOUT * 4;
  int* bsum    = (int*)(ws + off);      off += 4096;

  const int n16 = (int)(((size_t)VNUM * DMID * 4 + VNUM * 4) / 16);
  k_zero<<<2048, 256, 0, stream>>>((uint4*)zu, n16);

  k_hist<<<(E + 255) / 256, 256, 0, stream>>>(vid, cnt, E);
  k_scan_red<<<nb, 256, 0, stream>>>(cnt, bsum, VNUM);
  k_scan_top<<<1, 256, 0, stream>>>(bsum, nb);
  k_scan_fix<<<nb, 256, 0, stream>>>(cnt, bsum, VNUM);
  k_scatter<<<(E + 255) / 256, 256, 0, stream>>>(vid, cnt, sorted, E);

  k_gemm1_max<<<2048, 512, 0, stream>>>(x, vid, sorted, W1, b1, zu, ntiles);

  const int smY = (128 * 264 + 64 * 264) * sizeof(unsigned short);
  hipFuncSetAttribute((const void*)k_ymm,
                      hipFuncAttributeMaxDynamicSharedMemorySize, smY);
  k_ymm<<<782, 256, smY, stream>>>(zu, W2, Y, ntY);

  k_gemm2<<<768, 256, 0, stream>>>(x, vid, W2, Y, out, ntiles);
}

// Round 14
// 586.839 us; speedup vs baseline: 1.1149x; 1.0630x over previous
//
#include <hip/hip_runtime.h>

#define DIN   128
#define DMID  256
#define DOUT  128
#define VNUM  50000

typedef __attribute__((ext_vector_type(8))) __bf16 bf16x8;
typedef __attribute__((ext_vector_type(4))) float  f32x4;

// ---- conversions (native HW cvt, RNE) ----
static __device__ __forceinline__ unsigned short b16(float f) {
  union { __bf16 b; unsigned short u; } r; r.b = (__bf16)f; return r.u;
}
static __device__ __forceinline__ unsigned pk2(float lo, float hi) {
  union { __bf16 b[2]; unsigned u; } r;
  r.b[0] = (__bf16)lo; r.b[1] = (__bf16)hi;
  return r.u;
}
// ---- order-preserving monotone maps ----
static __device__ __forceinline__ unsigned unflip_bits(unsigned m) {
  unsigned mask = ((int)m < 0) ? 0x80000000u : 0xFFFFFFFFu;
  return m ^ mask;
}
static __device__ __forceinline__ unsigned flip32_from16(unsigned m) {
  return (m << 16) | ((m & 0x8000u) ? 0u : 0xFFFFu);
}

// LDS-only barrier: waits DS ops (lgkm) but does NOT drain vmcnt — in-flight
// scattered global stores cross the barrier and complete under the next
// phase's compute. __syncthreads() would emit s_waitcnt vmcnt(0) and
// serialize every tile on random-store completion (~900cy x2 per tile —
// the r2..r13 k1 256us invariant).
#define LBAR() do {                                            \
    __builtin_amdgcn_sched_barrier(0);                         \
    asm volatile("s_waitcnt lgkmcnt(0)" ::: "memory");         \
    __builtin_amdgcn_sched_barrier(0);                         \
    __builtin_amdgcn_s_barrier();                              \
    __builtin_amdgcn_sched_barrier(0);                         \
  } while (0)

// ---------------------------------------------------------------------------
// Custom zero-fill of zu+cnt (51.4MB).
// ---------------------------------------------------------------------------
__global__ __launch_bounds__(256) void k_zero(uint4* __restrict__ p, int n16) {
  const int stride = gridDim.x * 256;
  const uint4 z = {0u, 0u, 0u, 0u};
  for (int i = blockIdx.x * 256 + threadIdx.x; i < n16; i += stride) p[i] = z;
}

// ---------------------------------------------------------------------------
// Sort machinery: hist -> multi-block scan -> index scatter.
// ---------------------------------------------------------------------------
__global__ void k_hist(const int* __restrict__ vid, int* __restrict__ counts, int E) {
  int i = blockIdx.x * blockDim.x + threadIdx.x;
  if (i < E) atomicAdd(counts + vid[i], 1);
}

__global__ __launch_bounds__(256) void k_scan_red(
    const int* __restrict__ cnt, int* __restrict__ bsum, int V) {
  __shared__ int ws[4];
  const int i = blockIdx.x * 256 + threadIdx.x;
  int c = (i < V) ? cnt[i] : 0;
#pragma unroll
  for (int d = 1; d < 64; d <<= 1) c += __shfl_xor(c, d);
  if ((threadIdx.x & 63) == 0) ws[threadIdx.x >> 6] = c;
  __syncthreads();
  if (threadIdx.x == 0) bsum[blockIdx.x] = ws[0] + ws[1] + ws[2] + ws[3];
}

__global__ __launch_bounds__(256) void k_scan_top(int* __restrict__ bsum, int nb) {
  __shared__ int ws[4];
  const int tid = threadIdx.x, lane = tid & 63, wv = tid >> 6;
  int c = (tid < nb) ? bsum[tid] : 0;
  int s = c;
#pragma unroll
  for (int d = 1; d < 64; d <<= 1) {
    int u = __shfl_up(s, d, 64);
    if (lane >= d) s += u;
  }
  if (lane == 63) ws[wv] = s;
  __syncthreads();
  int off = 0;
  for (int k = 0; k < wv; ++k) off += ws[k];
  if (tid < nb) bsum[tid] = off + (s - c);
}

__global__ __launch_bounds__(256) void k_scan_fix(
    int* __restrict__ cursor, const int* __restrict__ bsum, int V) {
  __shared__ int ws[4];
  const int i = blockIdx.x * 256 + threadIdx.x;
  const int lane = threadIdx.x & 63, wv = threadIdx.x >> 6;
  int c = (i < V) ? cursor[i] : 0;
  int s = c;
#pragma unroll
  for (int d = 1; d < 64; d <<= 1) {
    int u = __shfl_up(s, d, 64);
    if (lane >= d) s += u;
  }
  if (lane == 63) ws[wv] = s;
  __syncthreads();
  int off = bsum[blockIdx.x];
  for (int k = 0; k < wv; ++k) off += ws[k];
  if (i < V) cursor[i] = off + (s - c);
}

__global__ void k_scatter(const int* __restrict__ vid, int* __restrict__ cursor,
                          int* __restrict__ sorted, int E) {
  int i = blockIdx.x * blockDim.x + threadIdx.x;
  if (i < E) {
    int v = vid[i];
    int p = atomicAdd(cursor + v, 1);
    sorted[p] = i;
  }
}

// ---------------------------------------------------------------------------
// Kernel 1: GEMM1 over sorted edges + segmented max.
// Phase layout per tile (2 LDS-only barriers, NO vmcnt drains in the loop):
//  P1: issue x-gather(t+G) + idx(t+2G); emask; MFMA(t); pack->zt   [LBAR]
//  P2: consume x loads -> write lx(t+1); sched_barrier; walk zt->zu
//      (scattered stores issued LAST, fly across the barrier)      [LBAR]
// Store-race freedom: plain stores only for runs interior to a tile (unique
// writer: a vertex's edges are contiguous in sorted order, and successive
// tiles of one block are G*64 edges apart >> max vertex multiplicity);
// boundary runs use device-scope atomicMax; kernel boundary orders zu
// before k_ymm.
// NOTE: NO min-waves hint (r5/r6: hints force spill-to-scratch; live ~116).
// ---------------------------------------------------------------------------
__global__ __launch_bounds__(512) void k_gemm1_max(
    const float* __restrict__ x, const int* __restrict__ vid,
    const int* __restrict__ sorted, const float* __restrict__ W1,
    const float* __restrict__ b1, unsigned* __restrict__ zu, int ntiles) {
  __shared__ unsigned short lx[64 * 136];   // x tile bf16 (row-major)
  __shared__ unsigned short zt[256 * 70];   // z tile, flipped bf16, [col][row]
  __shared__ int lvid[2][64];

  const int tid  = threadIdx.x;
  const int lane = tid & 63;
  const int w    = tid >> 6;       // 0..7
  const int l15  = lane & 15;
  const int l4   = lane >> 4;
  const int row8 = tid >> 3;       // staging: 8 threads per row
  const int s8   = tid & 7;        // 16 floats each
  const int G    = gridDim.x;

  // W1 fragments + bias for this wave's 32 cols
  bf16x8 bfrag[4][2];
  float  bias[2];
#pragma unroll
  for (int ni = 0; ni < 2; ++ni) {
    const int col = w * 32 + ni * 16 + l15;
    bias[ni] = b1[col];
#pragma unroll
    for (int kk = 0; kk < 4; ++kk) {
      union { bf16x8 v; unsigned short u[8]; } tmp;
#pragma unroll
      for (int j = 0; j < 8; ++j)
        tmp.u[j] = b16(W1[(kk * 32 + l4 * 8 + j) * DMID + col]);
      bfrag[kk][ni] = tmp.v;
    }
  }

  const int t0 = blockIdx.x;
  if (t0 >= ntiles) return;

  // ---- prologue: stage tile t0; prefetch indices for t0+G ----
  {
    if (tid < 64) lvid[0][tid] = vid[sorted[t0 * 64 + tid]];
    const int eid = sorted[t0 * 64 + row8];
    const float4* src =
        reinterpret_cast<const float4*>(x + (size_t)eid * DIN + s8 * 16);
#pragma unroll
    for (int i = 0; i < 4; ++i) {
      float4 v = src[i];
      uint2 o = { pk2(v.x, v.y), pk2(v.z, v.w) };
      *reinterpret_cast<uint2*>(&lx[row8 * 136 + s8 * 16 + i * 4]) = o;
    }
  }
  int eidN = 0, sidN = 0;
  bool moreP = (t0 + G) < ntiles;
  if (moreP) {
    eidN = sorted[(t0 + G) * 64 + row8];
    if (tid < 64) sidN = sorted[(t0 + G) * 64 + tid];
  }
  __syncthreads();   // full drain once, outside the steady loop

  int cur = 0;
  for (int t = t0; t < ntiles; t += G, cur ^= 1) {
    const bool more1 = (t + G) < ntiles;
    // ---- P1: issue x-gather for t+G (indices already in regs) ----
    float4 x0, x1, x2, x3;
    int vN = 0;
    if (more1) {
      const float4* src =
          reinterpret_cast<const float4*>(x + (size_t)eidN * DIN + s8 * 16);
      x0 = src[0]; x1 = src[1]; x2 = src[2]; x3 = src[3];
      if (tid < 64) vN = vid[sidN];
    }
    // prefetch indices for t+2G
    const bool more2 = (t + 2 * G) < ntiles;
    int eidN2 = 0, sidN2 = 0;
    if (more2) {
      eidN2 = sorted[(t + 2 * G) * 64 + row8];
      if (tid < 64) sidN2 = sorted[(t + 2 * G) * 64 + tid];
    }

    // uniform run-end mask (bit r = row r ends a vid run)
    const int myv = lvid[cur][lane];
    const int nv  = (lane == 63) ? (myv ^ 1) : lvid[cur][lane + 1];
    const unsigned long long emask = __ballot(myv != nv);
    const bool contOpen = (lvid[cur][31] == lvid[cur][32]);

    // ---- MFMA: 64 rows x 32 cols per wave, K=128 ----
    f32x4 acc[4][2];
#pragma unroll
    for (int mi = 0; mi < 4; ++mi)
#pragma unroll
      for (int ni = 0; ni < 2; ++ni)
        acc[mi][ni] = (f32x4){bias[ni], bias[ni], bias[ni], bias[ni]};
#pragma unroll
    for (int kk = 0; kk < 4; ++kk) {
      bf16x8 a[4];
#pragma unroll
      for (int mi = 0; mi < 4; ++mi)
        a[mi] = *reinterpret_cast<const bf16x8*>(
            &lx[(mi * 16 + l15) * 136 + kk * 32 + l4 * 8]);
#pragma unroll
      for (int mi = 0; mi < 4; ++mi)
#pragma unroll
        for (int ni = 0; ni < 2; ++ni)
          acc[mi][ni] = __builtin_amdgcn_mfma_f32_16x16x32_bf16(
              a[mi], bfrag[kk][ni], acc[mi][ni], 0, 0, 0);
    }

    // ---- pack acc -> zt (flipped bf16, column-major) ----
    {
      unsigned* ztw = reinterpret_cast<unsigned*>(zt);
#pragma unroll
      for (int ni = 0; ni < 2; ++ni) {
        const int col = w * 32 + ni * 16 + l15;
        const int cb  = col * 35 + l4 * 2;
#pragma unroll
        for (int mi = 0; mi < 4; ++mi)
#pragma unroll
          for (int p = 0; p < 2; ++p) {
            unsigned tpk = pk2(acc[mi][ni][2 * p], acc[mi][ni][2 * p + 1]);
            unsigned mflip = 0x80008000u + ((tpk >> 15) & 0x00010001u) * 0x7FFFu;
            ztw[cb + mi * 8 + p] = tpk ^ mflip;
          }
      }
    }
    LBAR();   // zt visible; lx consumed. NO vmcnt drain.

    // ---- P2a: consume x loads FIRST (before any new stores exist) ----
    if (more1) {
      uint2 o0 = { pk2(x0.x, x0.y), pk2(x0.z, x0.w) };
      uint2 o1 = { pk2(x1.x, x1.y), pk2(x1.z, x1.w) };
      uint2 o2 = { pk2(x2.x, x2.y), pk2(x2.z, x2.w) };
      uint2 o3 = { pk2(x3.x, x3.y), pk2(x3.z, x3.w) };
      unsigned short* dst = &lx[row8 * 136 + s8 * 16];
      *reinterpret_cast<uint2*>(dst + 0)  = o0;
      *reinterpret_cast<uint2*>(dst + 4)  = o1;
      *reinterpret_cast<uint2*>(dst + 8)  = o2;
      *reinterpret_cast<uint2*>(dst + 12) = o3;
      if (tid < 64) lvid[cur ^ 1][tid] = vN;
    }
    __builtin_amdgcn_sched_barrier(0);  // keep walk stores AFTER load-consume

    // ---- P2b: walk zt(t): 2 threads/col; stores issued fire-and-forget ----
    {
      const int col = tid & 255;
      const int h   = tid >> 8;
      const unsigned* zc = reinterpret_cast<const unsigned*>(&zt[col * 70 + h * 32]);
      unsigned curm = 0;
      bool first = true;
#pragma unroll
      for (int p = 0; p < 16; ++p) {
        const unsigned pr = zc[p];
#pragma unroll
        for (int j = 0; j < 2; ++j) {
          const unsigned val = j ? (pr >> 16) : (pr & 0xFFFFu);
          curm = val > curm ? val : curm;
          const int row = h * 32 + p * 2 + j;
          if ((emask >> row) & 1) {
            const int v = lvid[cur][row];
            const unsigned enc = flip32_from16(curm);
            unsigned* ad = zu + (size_t)v * DMID + col;
            if (row == 63 || (first && (h == 0 || contOpen))) atomicMax(ad, enc);
            else *ad = enc;
            curm = 0; first = false;
          }
        }
      }
      if (h == 0 && !((emask >> 31) & 1)) {  // trailing open run in top half
        const int v = lvid[cur][31];
        atomicMax(zu + (size_t)v * DMID + col, flip32_from16(curm));
      }
    }
    eidN = eidN2; sidN = sidN2;
    LBAR();   // lx/lvid staged; zt reads done. Stores drain under next MFMA.
  }
}

// ---------------------------------------------------------------------------
// Kernel Y: Y = unflip(zu) @ W2b  (V x 128). Block 256, wave 2x2.
// ---------------------------------------------------------------------------
__global__ __launch_bounds__(256) void k_ymm(
    const unsigned* __restrict__ zu, const float* __restrict__ W2,
    float* __restrict__ Y, int ntiles) {
  extern __shared__ unsigned short sm[];
  unsigned short* w2bt = sm;               // [128][264]
  unsigned short* za   = sm + 128 * 264;   // [64][264]

  const int tid  = threadIdx.x;
  const int lane = tid & 63;
  const int w    = tid >> 6;
  const int wr   = w >> 1, wc = w & 1;
  const int l15  = lane & 15, l4 = lane >> 4;

  {
    const int n = tid & 127, kh = tid >> 7;
    for (int k = kh * 128; k < kh * 128 + 128; ++k)
      w2bt[n * 264 + k] = b16(W2[(size_t)(DIN + k) * DOUT + n]);
  }
  __syncthreads();

  for (int t = blockIdx.x; t < ntiles; t += gridDim.x) {
    {
      const int row = tid >> 2, q = tid & 3;
      const int v = t * 64 + row;
      unsigned short* dz = &za[row * 264 + q * 64];
      if (v < VNUM) {
        const uint4* sz = reinterpret_cast<const uint4*>(zu + (size_t)v * DMID + q * 64);
#pragma unroll
        for (int i = 0; i < 16; ++i) {
          uint4 m = sz[i];
          ushort4 o = { (unsigned short)(unflip_bits(m.x) >> 16),
                        (unsigned short)(unflip_bits(m.y) >> 16),
                        (unsigned short)(unflip_bits(m.z) >> 16),
                        (unsigned short)(unflip_bits(m.w) >> 16) };
          *reinterpret_cast<ushort4*>(dz + i * 4) = o;
        }
      } else {
        ushort4 zo = {0, 0, 0, 0};
#pragma unroll
        for (int i = 0; i < 16; ++i) *reinterpret_cast<ushort4*>(dz + i * 4) = zo;
      }
    }
    __syncthreads();

    f32x4 acc[2][4];
#pragma unroll
    for (int mi = 0; mi < 2; ++mi)
#pragma unroll
      for (int ni = 0; ni < 4; ++ni) acc[mi][ni] = (f32x4){0.f, 0.f, 0.f, 0.f};

#pragma unroll
    for (int kk = 0; kk < 8; ++kk) {
      bf16x8 a[2], b[4];
#pragma unroll
      for (int mi = 0; mi < 2; ++mi)
        a[mi] = *reinterpret_cast<const bf16x8*>(
            &za[(wr * 32 + mi * 16 + l15) * 264 + kk * 32 + l4 * 8]);
#pragma unroll
      for (int ni = 0; ni < 4; ++ni)
        b[ni] = *reinterpret_cast<const bf16x8*>(
            &w2bt[(wc * 64 + ni * 16 + l15) * 264 + kk * 32 + l4 * 8]);
#pragma unroll
      for (int mi = 0; mi < 2; ++mi)
#pragma unroll
        for (int ni = 0; ni < 4; ++ni)
          acc[mi][ni] = __builtin_amdgcn_mfma_f32_16x16x32_bf16(
              a[mi], b[ni], acc[mi][ni], 0, 0, 0);
    }

#pragma unroll
    for (int mi = 0; mi < 2; ++mi)
#pragma unroll
      for (int r = 0; r < 4; ++r) {
        const int v = t * 64 + wr * 32 + mi * 16 + l4 * 4 + r;
        if (v < VNUM) {
          float* o = Y + (size_t)v * DOUT + wc * 64 + l15;
#pragma unroll
          for (int ni = 0; ni < 4; ++ni) o[ni * 16] = acc[mi][ni][r];
        }
      }
    __syncthreads();
  }
}

// ---------------------------------------------------------------------------
// Kernel 2: out = x @ W2a + Y[vid]  (original edge order). Block 256, wave
// 2x2; Y[vid] gathers issued before MFMA (latency hidden under compute).
// ---------------------------------------------------------------------------
__global__ __launch_bounds__(256, 3) void k_gemm2(
    const float* __restrict__ x, const int* __restrict__ vid,
    const float* __restrict__ W2, const float* __restrict__ Y,
    float* __restrict__ out, int ntiles) {
  __shared__ unsigned short w2at[128 * 136];
  __shared__ unsigned short lx[64 * 136];
  __shared__ int lvid[64];

  const int tid  = threadIdx.x;
  const int lane = tid & 63;
  const int w    = tid >> 6;
  const int wr   = w >> 1, wc = w & 1;
  const int l15  = lane & 15, l4 = lane >> 4;

  {
    const int n = tid & 127, kh = tid >> 7;
    for (int k = kh * 64; k < kh * 64 + 64; ++k)
      w2at[n * 136 + k] = b16(W2[(size_t)k * DOUT + n]);
  }
  __syncthreads();

  for (int t = blockIdx.x; t < ntiles; t += gridDim.x) {
    {
      const int row = tid >> 2, q = tid & 3;
      const float4* sx =
          reinterpret_cast<const float4*>(x + (size_t)(t * 64 + row) * DIN + q * 32);
#pragma unroll
      for (int i = 0; i < 8; ++i) {
        float4 v = sx[i];
        uint2 o = { pk2(v.x, v.y), pk2(v.z, v.w) };
        *reinterpret_cast<uint2*>(&lx[row * 136 + q * 32 + i * 4]) = o;
      }
      if (tid < 64) lvid[tid] = vid[t * 64 + tid];
    }
    __syncthreads();

    // ---- issue Y gathers (consumed after MFMA) ----
    float yv[2][4][4];  // [mi][r][ni]
#pragma unroll
    for (int mi = 0; mi < 2; ++mi)
#pragma unroll
      for (int r = 0; r < 4; ++r) {
        const int row = wr * 32 + mi * 16 + l4 * 4 + r;
        const float* Yr = Y + (size_t)lvid[row] * DOUT + wc * 64 + l15;
#pragma unroll
        for (int ni = 0; ni < 4; ++ni) yv[mi][r][ni] = Yr[ni * 16];
      }

    f32x4 acc[2][4];
#pragma unroll
    for (int mi = 0; mi < 2; ++mi)
#pragma unroll
      for (int ni = 0; ni < 4; ++ni) acc[mi][ni] = (f32x4){0.f, 0.f, 0.f, 0.f};

#pragma unroll
    for (int kk = 0; kk < 4; ++kk) {
      bf16x8 a[2], b[4];
#pragma unroll
      for (int mi = 0; mi < 2; ++mi)
        a[mi] = *reinterpret_cast<const bf16x8*>(
            &lx[(wr * 32 + mi * 16 + l15) * 136 + kk * 32 + l4 * 8]);
#pragma unroll
      for (int ni = 0; ni < 4; ++ni)
        b[ni] = *reinterpret_cast<const bf16x8*>(
            &w2at[(wc * 64 + ni * 16 + l15) * 136 + kk * 32 + l4 * 8]);
#pragma unroll
      for (int mi = 0; mi < 2; ++mi)
#pragma unroll
        for (int ni = 0; ni < 4; ++ni)
          acc[mi][ni] = __builtin_amdgcn_mfma_f32_16x16x32_bf16(
              a[mi], b[ni], acc[mi][ni], 0, 0, 0);
    }

#pragma unroll
    for (int mi = 0; mi < 2; ++mi)
#pragma unroll
      for (int r = 0; r < 4; ++r) {
        const int row = wr * 32 + mi * 16 + l4 * 4 + r;
        float* o = out + (size_t)(t * 64 + row) * DOUT + wc * 64 + l15;
#pragma unroll
        for (int ni = 0; ni < 4; ++ni) o[ni * 16] = acc[mi][ni][r] + yv[mi][r][ni];
      }
    __syncthreads();
  }
}

// ---------------------------------------------------------------------------
extern "C" void kernel_launch(void* const* d_in, const int* in_sizes, int n_in,
                              void* d_out, int out_size, void* d_ws, size_t ws_size,
                              hipStream_t stream) {
  const float* x   = (const float*)d_in[0];
  const int*   vid = (const int*)d_in[1];
  const float* W1  = (const float*)d_in[2];
  const float* b1  = (const float*)d_in[3];
  const float* W2  = (const float*)d_in[4];
  float* out = (float*)d_out;

  const int E = in_sizes[1];      // 800000 (divisible by 64)
  const int ntiles = E / 64;
  const int ntY = (VNUM + 63) / 64;   // 782
  const int nb = (VNUM + 255) / 256;  // 196 scan blocks

  char* ws = (char*)d_ws;
  size_t off = 0;
  unsigned* zu = (unsigned*)(ws + off); off += (size_t)VNUM * DMID * 4;
  int* cnt     = (int*)(ws + off);      off += (size_t)VNUM * 4;
  int* sorted  = (int*)(ws + off);      off += (size_t)E * 4;
  float* Y     = (float*)(ws + off);    off += (size_t)VNUM * DOUT * 4;
  int* bsum    = (int*)(ws + off);      off += 4096;

  const int n16 = (int)(((size_t)VNUM * DMID * 4 + VNUM * 4) / 16);
  k_zero<<<2048, 256, 0, stream>>>((uint4*)zu, n16);

  k_hist<<<(E + 255) / 256, 256, 0, stream>>>(vid, cnt, E);
  k_scan_red<<<nb, 256, 0, stream>>>(cnt, bsum, VNUM);
  k_scan_top<<<1, 256, 0, stream>>>(bsum, nb);
  k_scan_fix<<<nb, 256, 0, stream>>>(cnt, bsum, VNUM);
  k_scatter<<<(E + 255) / 256, 256, 0, stream>>>(vid, cnt, sorted, E);

  // persistent grid: 2 resident blocks/CU x 256 CUs; prologue paid once
  k_gemm1_max<<<512, 512, 0, stream>>>(x, vid, sorted, W1, b1, zu, ntiles);

  const int smY = (128 * 264 + 64 * 264) * sizeof(unsigned short);
  hipFuncSetAttribute((const void*)k_ymm,
                      hipFuncAttributeMaxDynamicSharedMemorySize, smY);
  k_ymm<<<782, 256, smY, stream>>>(zu, W2, Y, ntY);

  k_gemm2<<<768, 256, 0, stream>>>(x, vid, W2, Y, out, ntiles);
}

// Round 15
// 566.563 us; speedup vs baseline: 1.1549x; 1.0358x over previous
//
#include <hip/hip_runtime.h>

#define DIN   128
#define DMID  256
#define DOUT  128
#define VNUM  50000

typedef __attribute__((ext_vector_type(8))) __bf16 bf16x8;
typedef __attribute__((ext_vector_type(4))) float  f32x4;

// ---- conversions (native HW cvt, RNE) ----
static __device__ __forceinline__ unsigned short b16(float f) {
  union { __bf16 b; unsigned short u; } r; r.b = (__bf16)f; return r.u;
}
static __device__ __forceinline__ unsigned pk2(float lo, float hi) {
  union { __bf16 b[2]; unsigned u; } r;
  r.b[0] = (__bf16)lo; r.b[1] = (__bf16)hi;
  return r.u;
}
// ---- order-preserving monotone maps ----
static __device__ __forceinline__ unsigned unflip_bits(unsigned m) {
  unsigned mask = ((int)m < 0) ? 0x80000000u : 0xFFFFFFFFu;
  return m ^ mask;
}
static __device__ __forceinline__ unsigned flip32_from16(unsigned m) {
  return (m << 16) | ((m & 0x8000u) ? 0u : 0xFFFFu);
}

// LDS-only barrier: waits DS ops (lgkm) but does NOT drain vmcnt — in-flight
// scattered global stores/gathers cross the barrier and complete under the
// next phase's compute. __syncthreads() emits s_waitcnt vmcnt(0) and
// serialized every tile on random-store completion (r2..r13 k1 invariant;
// removing it was r14's 624->587).
#define LBAR() do {                                            \
    __builtin_amdgcn_sched_barrier(0);                         \
    asm volatile("s_waitcnt lgkmcnt(0)" ::: "memory");         \
    __builtin_amdgcn_sched_barrier(0);                         \
    __builtin_amdgcn_s_barrier();                              \
    __builtin_amdgcn_sched_barrier(0);                         \
  } while (0)

// ---------------------------------------------------------------------------
// Custom zero-fill of zu+cnt (51.4MB).
// ---------------------------------------------------------------------------
__global__ __launch_bounds__(256) void k_zero(uint4* __restrict__ p, int n16) {
  const int stride = gridDim.x * 256;
  const uint4 z = {0u, 0u, 0u, 0u};
  for (int i = blockIdx.x * 256 + threadIdx.x; i < n16; i += stride) p[i] = z;
}

// ---------------------------------------------------------------------------
// Sort machinery: hist -> multi-block scan -> index scatter.
// ---------------------------------------------------------------------------
__global__ void k_hist(const int* __restrict__ vid, int* __restrict__ counts, int E) {
  int i = blockIdx.x * blockDim.x + threadIdx.x;
  if (i < E) atomicAdd(counts + vid[i], 1);
}

__global__ __launch_bounds__(256) void k_scan_red(
    const int* __restrict__ cnt, int* __restrict__ bsum, int V) {
  __shared__ int ws[4];
  const int i = blockIdx.x * 256 + threadIdx.x;
  int c = (i < V) ? cnt[i] : 0;
#pragma unroll
  for (int d = 1; d < 64; d <<= 1) c += __shfl_xor(c, d);
  if ((threadIdx.x & 63) == 0) ws[threadIdx.x >> 6] = c;
  __syncthreads();
  if (threadIdx.x == 0) bsum[blockIdx.x] = ws[0] + ws[1] + ws[2] + ws[3];
}

__global__ __launch_bounds__(256) void k_scan_top(int* __restrict__ bsum, int nb) {
  __shared__ int ws[4];
  const int tid = threadIdx.x, lane = tid & 63, wv = tid >> 6;
  int c = (tid < nb) ? bsum[tid] : 0;
  int s = c;
#pragma unroll
  for (int d = 1; d < 64; d <<= 1) {
    int u = __shfl_up(s, d, 64);
    if (lane >= d) s += u;
  }
  if (lane == 63) ws[wv] = s;
  __syncthreads();
  int off = 0;
  for (int k = 0; k < wv; ++k) off += ws[k];
  if (tid < nb) bsum[tid] = off + (s - c);
}

__global__ __launch_bounds__(256) void k_scan_fix(
    int* __restrict__ cursor, const int* __restrict__ bsum, int V) {
  __shared__ int ws[4];
  const int i = blockIdx.x * 256 + threadIdx.x;
  const int lane = threadIdx.x & 63, wv = threadIdx.x >> 6;
  int c = (i < V) ? cursor[i] : 0;
  int s = c;
#pragma unroll
  for (int d = 1; d < 64; d <<= 1) {
    int u = __shfl_up(s, d, 64);
    if (lane >= d) s += u;
  }
  if (lane == 63) ws[wv] = s;
  __syncthreads();
  int off = bsum[blockIdx.x];
  for (int k = 0; k < wv; ++k) off += ws[k];
  if (i < V) cursor[i] = off + (s - c);
}

__global__ void k_scatter(const int* __restrict__ vid, int* __restrict__ cursor,
                          int* __restrict__ sorted, int E) {
  int i = blockIdx.x * blockDim.x + threadIdx.x;
  if (i < E) {
    int v = vid[i];
    int p = atomicAdd(cursor + v, 1);
    sorted[p] = i;
  }
}

// ---------------------------------------------------------------------------
// Kernel 1: GEMM1 over sorted edges + segmented max.
// TILE = 32 edges x 256 cols, block = 256 thr (4 waves of 32r x 64c).
// Rationale (r14 model): per-wave MFMA per tile is unchanged (32) while the
// gather per tile halves -> latency cover-ratio doubles; live set ~104 VGPR
// -> ~4 blocks/CU resident (vs 2 at the 512-thr/64-row shape) -> 2x TLP
// across the gather/walk phases. Full 256 cols stay in ONE block (r10 lesson:
// no cross-block row sharing / XCD L2 blowup).
// Phase layout per tile (2 LDS-only barriers, NO vmcnt drains in loop):
//  P1: issue x-gather(t+G) + idx(t+2G); emask; MFMA(t); pack->zt  [LBAR]
//  P2: consume x loads -> lx(t+1); sched_barrier; walk zt->zu     [LBAR]
// Walk store-race freedom: interior runs have a unique writer (sorted
// contiguity); first run and run ending at row 31 use device-scope atomicMax.
// NOTE: NO min-waves hint (r5/r6: hints force spill-to-scratch).
// ---------------------------------------------------------------------------
__global__ __launch_bounds__(256) void k_gemm1_max(
    const float* __restrict__ x, const int* __restrict__ vid,
    const int* __restrict__ sorted, const float* __restrict__ W1,
    const float* __restrict__ b1, unsigned* __restrict__ zu, int ntiles) {
  __shared__ unsigned short lx[32 * 136];   // x tile bf16 (row-major)
  __shared__ unsigned zt[256 * 17];         // z tile, flipped bf16 pairs [col][row/2]
  __shared__ int lvid[2][32];

  const int tid  = threadIdx.x;
  const int lane = tid & 63;
  const int w    = tid >> 6;       // 0..3 -> col slice w*64
  const int l15  = lane & 15;
  const int l4   = lane >> 4;
  const int row8 = tid >> 3;       // staging: 8 threads per row (32 rows)
  const int s8   = tid & 7;        // 16 floats each
  const int G    = gridDim.x;

  // W1 fragments + bias for this wave's 64 cols
  bf16x8 bfrag[4][4];
  float  bias[4];
#pragma unroll
  for (int ni = 0; ni < 4; ++ni) {
    const int col = w * 64 + ni * 16 + l15;
    bias[ni] = b1[col];
#pragma unroll
    for (int kk = 0; kk < 4; ++kk) {
      union { bf16x8 v; unsigned short u[8]; } tmp;
#pragma unroll
      for (int j = 0; j < 8; ++j)
        tmp.u[j] = b16(W1[(kk * 32 + l4 * 8 + j) * DMID + col]);
      bfrag[kk][ni] = tmp.v;
    }
  }

  const int t0 = blockIdx.x;
  if (t0 >= ntiles) return;

  // ---- prologue: stage tile t0; prefetch indices for t0+G ----
  {
    if (tid < 32) lvid[0][tid] = vid[sorted[t0 * 32 + tid]];
    const int eid = sorted[t0 * 32 + row8];
    const float4* src =
        reinterpret_cast<const float4*>(x + (size_t)eid * DIN + s8 * 16);
#pragma unroll
    for (int i = 0; i < 4; ++i) {
      float4 v = src[i];
      uint2 o = { pk2(v.x, v.y), pk2(v.z, v.w) };
      *reinterpret_cast<uint2*>(&lx[row8 * 136 + s8 * 16 + i * 4]) = o;
    }
  }
  int eidN = 0, sidN = 0;
  if ((t0 + G) < ntiles) {
    eidN = sorted[(t0 + G) * 32 + row8];
    if (tid < 32) sidN = sorted[(t0 + G) * 32 + tid];
  }
  __syncthreads();   // full drain once, outside the steady loop

  int cur = 0;
  for (int t = t0; t < ntiles; t += G, cur ^= 1) {
    const bool more1 = (t + G) < ntiles;
    // ---- P1: issue x-gather for t+G (indices already in regs) ----
    float4 x0, x1, x2, x3;
    int vN = 0;
    if (more1) {
      const float4* src =
          reinterpret_cast<const float4*>(x + (size_t)eidN * DIN + s8 * 16);
      x0 = src[0]; x1 = src[1]; x2 = src[2]; x3 = src[3];
      if (tid < 32) vN = vid[sidN];
    }
    // prefetch indices for t+2G
    const bool more2 = (t + 2 * G) < ntiles;
    int eidN2 = 0, sidN2 = 0;
    if (more2) {
      eidN2 = sorted[(t + 2 * G) * 32 + row8];
      if (tid < 32) sidN2 = sorted[(t + 2 * G) * 32 + tid];
    }

    // uniform run-end mask over 32 rows (bit r = row r ends a vid run)
    const int r32  = lane & 31;
    const int myv  = lvid[cur][r32];
    const int nv   = (r32 == 31) ? (myv ^ 1) : lvid[cur][r32 + 1];
    const unsigned emask = (unsigned)(__ballot(myv != nv) & 0xFFFFFFFFull);

    // ---- MFMA: 32 rows x 64 cols per wave, K=128 ----
    f32x4 acc[2][4];
#pragma unroll
    for (int mi = 0; mi < 2; ++mi)
#pragma unroll
      for (int ni = 0; ni < 4; ++ni)
        acc[mi][ni] = (f32x4){bias[ni], bias[ni], bias[ni], bias[ni]};
#pragma unroll
    for (int kk = 0; kk < 4; ++kk) {
      bf16x8 a[2];
#pragma unroll
      for (int mi = 0; mi < 2; ++mi)
        a[mi] = *reinterpret_cast<const bf16x8*>(
            &lx[(mi * 16 + l15) * 136 + kk * 32 + l4 * 8]);
#pragma unroll
      for (int mi = 0; mi < 2; ++mi)
#pragma unroll
        for (int ni = 0; ni < 4; ++ni)
          acc[mi][ni] = __builtin_amdgcn_mfma_f32_16x16x32_bf16(
              a[mi], bfrag[kk][ni], acc[mi][ni], 0, 0, 0);
    }

    // ---- pack acc -> zt (flipped bf16 pairs, [col][row/2], stride 17) ----
#pragma unroll
    for (int ni = 0; ni < 4; ++ni) {
      const int col = w * 64 + ni * 16 + l15;
      const int cb  = col * 17 + l4 * 2;
#pragma unroll
      for (int mi = 0; mi < 2; ++mi)
#pragma unroll
        for (int p = 0; p < 2; ++p) {
          unsigned tpk = pk2(acc[mi][ni][2 * p], acc[mi][ni][2 * p + 1]);
          unsigned mflip = 0x80008000u + ((tpk >> 15) & 0x00010001u) * 0x7FFFu;
          zt[cb + mi * 8 + p] = tpk ^ mflip;
        }
    }
    LBAR();   // zt visible; lx consumed. NO vmcnt drain.

    // ---- P2a: consume x loads FIRST (before any new stores exist) ----
    if (more1) {
      uint2 o0 = { pk2(x0.x, x0.y), pk2(x0.z, x0.w) };
      uint2 o1 = { pk2(x1.x, x1.y), pk2(x1.z, x1.w) };
      uint2 o2 = { pk2(x2.x, x2.y), pk2(x2.z, x2.w) };
      uint2 o3 = { pk2(x3.x, x3.y), pk2(x3.z, x3.w) };
      unsigned short* dst = &lx[row8 * 136 + s8 * 16];
      *reinterpret_cast<uint2*>(dst + 0)  = o0;
      *reinterpret_cast<uint2*>(dst + 4)  = o1;
      *reinterpret_cast<uint2*>(dst + 8)  = o2;
      *reinterpret_cast<uint2*>(dst + 12) = o3;
      if (tid < 32) lvid[cur ^ 1][tid] = vN;
    }
    __builtin_amdgcn_sched_barrier(0);  // keep walk stores AFTER load-consume

    // ---- P2b: walk zt(t): 1 thread/col, 32 rows; stores fire-and-forget ----
    {
      const int col = tid;
      const unsigned* zc = &zt[col * 17];
      unsigned curm = 0;
      bool first = true;
#pragma unroll
      for (int p = 0; p < 16; ++p) {
        const unsigned pr = zc[p];
#pragma unroll
        for (int j = 0; j < 2; ++j) {
          const unsigned val = j ? (pr >> 16) : (pr & 0xFFFFu);
          curm = val > curm ? val : curm;
          const int row = p * 2 + j;
          if ((emask >> row) & 1) {
            const int v = lvid[cur][row];
            const unsigned enc = flip32_from16(curm);
            unsigned* ad = zu + (size_t)v * DMID + col;
            if (first || row == 31) atomicMax(ad, enc);
            else *ad = enc;
            curm = 0; first = false;
          }
        }
      }
    }
    eidN = eidN2; sidN = sidN2;
    LBAR();   // lx/lvid staged; zt reads done. Stores drain under next MFMA.
  }
}

// ---------------------------------------------------------------------------
// Kernel Y: Y = unflip(zu) @ W2b  (V x 128). Block 256, wave 2x2.
// ---------------------------------------------------------------------------
__global__ __launch_bounds__(256) void k_ymm(
    const unsigned* __restrict__ zu, const float* __restrict__ W2,
    float* __restrict__ Y, int ntiles) {
  extern __shared__ unsigned short sm[];
  unsigned short* w2bt = sm;               // [128][264]
  unsigned short* za   = sm + 128 * 264;   // [64][264]

  const int tid  = threadIdx.x;
  const int lane = tid & 63;
  const int w    = tid >> 6;
  const int wr   = w >> 1, wc = w & 1;
  const int l15  = lane & 15, l4 = lane >> 4;

  {
    const int n = tid & 127, kh = tid >> 7;
    for (int k = kh * 128; k < kh * 128 + 128; ++k)
      w2bt[n * 264 + k] = b16(W2[(size_t)(DIN + k) * DOUT + n]);
  }
  __syncthreads();

  for (int t = blockIdx.x; t < ntiles; t += gridDim.x) {
    {
      const int row = tid >> 2, q = tid & 3;
      const int v = t * 64 + row;
      unsigned short* dz = &za[row * 264 + q * 64];
      if (v < VNUM) {
        const uint4* sz = reinterpret_cast<const uint4*>(zu + (size_t)v * DMID + q * 64);
#pragma unroll
        for (int i = 0; i < 16; ++i) {
          uint4 m = sz[i];
          ushort4 o = { (unsigned short)(unflip_bits(m.x) >> 16),
                        (unsigned short)(unflip_bits(m.y) >> 16),
                        (unsigned short)(unflip_bits(m.z) >> 16),
                        (unsigned short)(unflip_bits(m.w) >> 16) };
          *reinterpret_cast<ushort4*>(dz + i * 4) = o;
        }
      } else {
        ushort4 zo = {0, 0, 0, 0};
#pragma unroll
        for (int i = 0; i < 16; ++i) *reinterpret_cast<ushort4*>(dz + i * 4) = zo;
      }
    }
    __syncthreads();

    f32x4 acc[2][4];
#pragma unroll
    for (int mi = 0; mi < 2; ++mi)
#pragma unroll
      for (int ni = 0; ni < 4; ++ni) acc[mi][ni] = (f32x4){0.f, 0.f, 0.f, 0.f};

#pragma unroll
    for (int kk = 0; kk < 8; ++kk) {
      bf16x8 a[2], b[4];
#pragma unroll
      for (int mi = 0; mi < 2; ++mi)
        a[mi] = *reinterpret_cast<const bf16x8*>(
            &za[(wr * 32 + mi * 16 + l15) * 264 + kk * 32 + l4 * 8]);
#pragma unroll
      for (int ni = 0; ni < 4; ++ni)
        b[ni] = *reinterpret_cast<const bf16x8*>(
            &w2bt[(wc * 64 + ni * 16 + l15) * 264 + kk * 32 + l4 * 8]);
#pragma unroll
      for (int mi = 0; mi < 2; ++mi)
#pragma unroll
        for (int ni = 0; ni < 4; ++ni)
          acc[mi][ni] = __builtin_amdgcn_mfma_f32_16x16x32_bf16(
              a[mi], b[ni], acc[mi][ni], 0, 0, 0);
    }

#pragma unroll
    for (int mi = 0; mi < 2; ++mi)
#pragma unroll
      for (int r = 0; r < 4; ++r) {
        const int v = t * 64 + wr * 32 + mi * 16 + l4 * 4 + r;
        if (v < VNUM) {
          float* o = Y + (size_t)v * DOUT + wc * 64 + l15;
#pragma unroll
          for (int ni = 0; ni < 4; ++ni) o[ni * 16] = acc[mi][ni][r];
        }
      }
    __syncthreads();
  }
}

// ---------------------------------------------------------------------------
// Kernel 2: out = x @ W2a + Y[vid]  (original edge order). Block 256, wave
// 2x2; Y[vid] gathers issued before MFMA; LDS-only barriers (out-stores and
// Y-gathers need no vmcnt drain — same r14 lever as k1).
// ---------------------------------------------------------------------------
__global__ __launch_bounds__(256, 3) void k_gemm2(
    const float* __restrict__ x, const int* __restrict__ vid,
    const float* __restrict__ W2, const float* __restrict__ Y,
    float* __restrict__ out, int ntiles) {
  __shared__ unsigned short w2at[128 * 136];
  __shared__ unsigned short lx[64 * 136];
  __shared__ int lvid[64];

  const int tid  = threadIdx.x;
  const int lane = tid & 63;
  const int w    = tid >> 6;
  const int wr   = w >> 1, wc = w & 1;
  const int l15  = lane & 15, l4 = lane >> 4;

  {
    const int n = tid & 127, kh = tid >> 7;
    for (int k = kh * 64; k < kh * 64 + 64; ++k)
      w2at[n * 136 + k] = b16(W2[(size_t)k * DOUT + n]);
  }
  __syncthreads();

  for (int t = blockIdx.x; t < ntiles; t += gridDim.x) {
    {
      const int row = tid >> 2, q = tid & 3;
      const float4* sx =
          reinterpret_cast<const float4*>(x + (size_t)(t * 64 + row) * DIN + q * 32);
#pragma unroll
      for (int i = 0; i < 8; ++i) {
        float4 v = sx[i];
        uint2 o = { pk2(v.x, v.y), pk2(v.z, v.w) };
        *reinterpret_cast<uint2*>(&lx[row * 136 + q * 32 + i * 4]) = o;
      }
      if (tid < 64) lvid[tid] = vid[t * 64 + tid];
    }
    LBAR();

    // ---- issue Y gathers (consumed after MFMA) ----
    float yv[2][4][4];  // [mi][r][ni]
#pragma unroll
    for (int mi = 0; mi < 2; ++mi)
#pragma unroll
      for (int r = 0; r < 4; ++r) {
        const int row = wr * 32 + mi * 16 + l4 * 4 + r;
        const float* Yr = Y + (size_t)lvid[row] * DOUT + wc * 64 + l15;
#pragma unroll
        for (int ni = 0; ni < 4; ++ni) yv[mi][r][ni] = Yr[ni * 16];
      }

    f32x4 acc[2][4];
#pragma unroll
    for (int mi = 0; mi < 2; ++mi)
#pragma unroll
      for (int ni = 0; ni < 4; ++ni) acc[mi][ni] = (f32x4){0.f, 0.f, 0.f, 0.f};

#pragma unroll
    for (int kk = 0; kk < 4; ++kk) {
      bf16x8 a[2], b[4];
#pragma unroll
      for (int mi = 0; mi < 2; ++mi)
        a[mi] = *reinterpret_cast<const bf16x8*>(
            &lx[(wr * 32 + mi * 16 + l15) * 136 + kk * 32 + l4 * 8]);
#pragma unroll
      for (int ni = 0; ni < 4; ++ni)
        b[ni] = *reinterpret_cast<const bf16x8*>(
            &w2at[(wc * 64 + ni * 16 + l15) * 136 + kk * 32 + l4 * 8]);
#pragma unroll
      for (int mi = 0; mi < 2; ++mi)
#pragma unroll
        for (int ni = 0; ni < 4; ++ni)
          acc[mi][ni] = __builtin_amdgcn_mfma_f32_16x16x32_bf16(
              a[mi], b[ni], acc[mi][ni], 0, 0, 0);
    }

#pragma unroll
    for (int mi = 0; mi < 2; ++mi)
#pragma unroll
      for (int r = 0; r < 4; ++r) {
        const int row = wr * 32 + mi * 16 + l4 * 4 + r;
        float* o = out + (size_t)(t * 64 + row) * DOUT + wc * 64 + l15;
#pragma unroll
        for (int ni = 0; ni < 4; ++ni) o[ni * 16] = acc[mi][ni][r] + yv[mi][r][ni];
      }
    LBAR();
  }
}

// ---------------------------------------------------------------------------
extern "C" void kernel_launch(void* const* d_in, const int* in_sizes, int n_in,
                              void* d_out, int out_size, void* d_ws, size_t ws_size,
                              hipStream_t stream) {
  const float* x   = (const float*)d_in[0];
  const int*   vid = (const int*)d_in[1];
  const float* W1  = (const float*)d_in[2];
  const float* b1  = (const float*)d_in[3];
  const float* W2  = (const float*)d_in[4];
  float* out = (float*)d_out;

  const int E = in_sizes[1];          // 800000
  const int ntiles32 = E / 32;        // 25000 (E divisible by 64)
  const int ntiles64 = E / 64;        // 12500
  const int ntY = (VNUM + 63) / 64;   // 782
  const int nb = (VNUM + 255) / 256;  // 196 scan blocks

  char* ws = (char*)d_ws;
  size_t off = 0;
  unsigned* zu = (unsigned*)(ws + off); off += (size_t)VNUM * DMID * 4;
  int* cnt     = (int*)(ws + off);      off += (size_t)VNUM * 4;
  int* sorted  = (int*)(ws + off);      off += (size_t)E * 4;
  float* Y     = (float*)(ws + off);    off += (size_t)VNUM * DOUT * 4;
  int* bsum    = (int*)(ws + off);      off += 4096;

  const int n16 = (int)(((size_t)VNUM * DMID * 4 + VNUM * 4) / 16);
  k_zero<<<2048, 256, 0, stream>>>((uint4*)zu, n16);

  k_hist<<<(E + 255) / 256, 256, 0, stream>>>(vid, cnt, E);
  k_scan_red<<<nb, 256, 0, stream>>>(cnt, bsum, VNUM);
  k_scan_top<<<1, 256, 0, stream>>>(bsum, nb);
  k_scan_fix<<<nb, 256, 0, stream>>>(cnt, bsum, VNUM);
  k_scatter<<<(E + 255) / 256, 256, 0, stream>>>(vid, cnt, sorted, E);

  // persistent grid: ~4 blocks/CU x 256 CUs
  k_gemm1_max<<<1024, 256, 0, stream>>>(x, vid, sorted, W1, b1, zu, ntiles32);

  const int smY = (128 * 264 + 64 * 264) * sizeof(unsigned short);
  hipFuncSetAttribute((const void*)k_ymm,
                      hipFuncAttributeMaxDynamicSharedMemorySize, smY);
  k_ymm<<<782, 256, smY, stream>>>(zu, W2, Y, ntY);

  k_gemm2<<<768, 256, 0, stream>>>(x, vid, W2, Y, out, ntiles64);
}

// Round 16
// 537.394 us; speedup vs baseline: 1.2175x; 1.0543x over previous
//
#include <hip/hip_runtime.h>

#define DIN   128
#define DMID  256
#define DOUT  128
#define VNUM  50000

typedef __attribute__((ext_vector_type(8))) __bf16 bf16x8;
typedef __attribute__((ext_vector_type(4))) float  f32x4;

// ---- conversions (native HW cvt, RNE) ----
static __device__ __forceinline__ unsigned short b16(float f) {
  union { __bf16 b; unsigned short u; } r; r.b = (__bf16)f; return r.u;
}
static __device__ __forceinline__ unsigned pk2(float lo, float hi) {
  union { __bf16 b[2]; unsigned u; } r;
  r.b[0] = (__bf16)lo; r.b[1] = (__bf16)hi;
  return r.u;
}
// ---- order-preserving monotone maps ----
static __device__ __forceinline__ unsigned unflip_bits(unsigned m) {
  unsigned mask = ((int)m < 0) ? 0x80000000u : 0xFFFFFFFFu;
  return m ^ mask;
}
static __device__ __forceinline__ unsigned flip32_from16(unsigned m) {
  return (m << 16) | ((m & 0x8000u) ? 0u : 0xFFFFu);
}

// LDS-only barrier: waits DS ops (lgkm) but does NOT drain vmcnt — in-flight
// scattered global stores/gathers cross the barrier and complete under the
// next phase's compute (r14: removing the vmcnt drain was 624->587).
#define LBAR() do {                                            \
    __builtin_amdgcn_sched_barrier(0);                         \
    asm volatile("s_waitcnt lgkmcnt(0)" ::: "memory");         \
    __builtin_amdgcn_sched_barrier(0);                         \
    __builtin_amdgcn_s_barrier();                              \
    __builtin_amdgcn_sched_barrier(0);                         \
  } while (0)

// ---------------------------------------------------------------------------
// Custom zero-fill of zu+cnt (51.4MB).
// ---------------------------------------------------------------------------
__global__ __launch_bounds__(256) void k_zero(uint4* __restrict__ p, int n16) {
  const int stride = gridDim.x * 256;
  const uint4 z = {0u, 0u, 0u, 0u};
  for (int i = blockIdx.x * 256 + threadIdx.x; i < n16; i += stride) p[i] = z;
}

// ---------------------------------------------------------------------------
// Sort machinery: hist -> multi-block scan -> index scatter.
// ---------------------------------------------------------------------------
__global__ void k_hist(const int* __restrict__ vid, int* __restrict__ counts, int E) {
  int i = blockIdx.x * blockDim.x + threadIdx.x;
  if (i < E) atomicAdd(counts + vid[i], 1);
}

__global__ __launch_bounds__(256) void k_scan_red(
    const int* __restrict__ cnt, int* __restrict__ bsum, int V) {
  __shared__ int ws[4];
  const int i = blockIdx.x * 256 + threadIdx.x;
  int c = (i < V) ? cnt[i] : 0;
#pragma unroll
  for (int d = 1; d < 64; d <<= 1) c += __shfl_xor(c, d);
  if ((threadIdx.x & 63) == 0) ws[threadIdx.x >> 6] = c;
  __syncthreads();
  if (threadIdx.x == 0) bsum[blockIdx.x] = ws[0] + ws[1] + ws[2] + ws[3];
}

__global__ __launch_bounds__(256) void k_scan_top(int* __restrict__ bsum, int nb) {
  __shared__ int ws[4];
  const int tid = threadIdx.x, lane = tid & 63, wv = tid >> 6;
  int c = (tid < nb) ? bsum[tid] : 0;
  int s = c;
#pragma unroll
  for (int d = 1; d < 64; d <<= 1) {
    int u = __shfl_up(s, d, 64);
    if (lane >= d) s += u;
  }
  if (lane == 63) ws[wv] = s;
  __syncthreads();
  int off = 0;
  for (int k = 0; k < wv; ++k) off += ws[k];
  if (tid < nb) bsum[tid] = off + (s - c);
}

__global__ __launch_bounds__(256) void k_scan_fix(
    int* __restrict__ cursor, const int* __restrict__ bsum, int V) {
  __shared__ int ws[4];
  const int i = blockIdx.x * 256 + threadIdx.x;
  const int lane = threadIdx.x & 63, wv = threadIdx.x >> 6;
  int c = (i < V) ? cursor[i] : 0;
  int s = c;
#pragma unroll
  for (int d = 1; d < 64; d <<= 1) {
    int u = __shfl_up(s, d, 64);
    if (lane >= d) s += u;
  }
  if (lane == 63) ws[wv] = s;
  __syncthreads();
  int off = bsum[blockIdx.x];
  for (int k = 0; k < wv; ++k) off += ws[k];
  if (i < V) cursor[i] = off + (s - c);
}

__global__ void k_scatter(const int* __restrict__ vid, int* __restrict__ cursor,
                          int* __restrict__ sorted, int E) {
  int i = blockIdx.x * blockDim.x + threadIdx.x;
  if (i < E) {
    int v = vid[i];
    int p = atomicAdd(cursor + v, 1);
    sorted[p] = i;
  }
}

// ---------------------------------------------------------------------------
// Kernel 1: GEMM1 over sorted edges + segmented max.
// TILE = 32 edges x 256 cols, block 256 (4 waves of 32r x 64c), persistent.
// 2-DEEP register gather pipeline (this round): buffer issued at iteration
// i's P1 is consumed at iteration i+1's P2a (~1.5 iterations in flight,
// fully covering ~900cy random-row HBM latency). Two NAMED buffers A/B with
// a 2x-unrolled loop — no runtime buffer index (scratch trap), no copies.
// Phases per tile (2 LDS-only barriers, no vmcnt drains in loop):
//  P1: issue gather(t+2G)->other buf; refill idx(t+3G); emask; MFMA; pack
//  [LBAR]  P2a: consume this buf -> lx(t+G); sched_barrier; P2b: walk  [LBAR]
// Walk store-race freedom: interior runs unique-writer (sorted contiguity);
// first run / run ending at row 31 use device-scope atomicMax.
// NOTE: NO min-waves hint (r5/r6: hints force spill-to-scratch).
// ---------------------------------------------------------------------------
#define K1_ITER(TT, CA0, CA1, CA2, CA3, CAV, CAM, IB0, IB1, IB2, IB3, IBV, IBM, PCUR) \
  {                                                                                    \
    /* P1: issue gather for (TT+2G) into issue-buffer */                               \
    IBM = (TT + 2 * G) < ntiles;                                                       \
    if (IBM) {                                                                         \
      const float4* _src =                                                             \
          reinterpret_cast<const float4*>(x + (size_t)eidI * DIN + s8 * 16);           \
      IB0 = _src[0]; IB1 = _src[1]; IB2 = _src[2]; IB3 = _src[3];                      \
      if (tid < 32) IBV = vid[sidI];                                                   \
    }                                                                                  \
    if ((TT + 3 * G) < ntiles) {   /* refill idx pair for TT+3G */                     \
      eidI = sorted[(TT + 3 * G) * 32 + row8];                                         \
      if (tid < 32) sidI = sorted[(TT + 3 * G) * 32 + tid];                            \
    }                                                                                  \
    /* uniform run-end mask over 32 rows */                                            \
    const int _myv = lvid[PCUR][r32];                                                  \
    const int _nv  = (r32 == 31) ? (_myv ^ 1) : lvid[PCUR][r32 + 1];                   \
    const unsigned _emask = (unsigned)(__ballot(_myv != _nv) & 0xFFFFFFFFull);         \
    /* MFMA: 32r x 64c per wave, K=128 */                                              \
    f32x4 _acc[2][4];                                                                  \
    _Pragma("unroll") for (int mi = 0; mi < 2; ++mi)                                   \
      _Pragma("unroll") for (int ni = 0; ni < 4; ++ni)                                 \
        _acc[mi][ni] = (f32x4){bias[ni], bias[ni], bias[ni], bias[ni]};                \
    _Pragma("unroll") for (int kk = 0; kk < 4; ++kk) {                                 \
      bf16x8 _a[2];                                                                    \
      _Pragma("unroll") for (int mi = 0; mi < 2; ++mi)                                 \
        _a[mi] = *reinterpret_cast<const bf16x8*>(                                     \
            &lx[(mi * 16 + l15) * 136 + kk * 32 + l4 * 8]);                            \
      _Pragma("unroll") for (int mi = 0; mi < 2; ++mi)                                 \
        _Pragma("unroll") for (int ni = 0; ni < 4; ++ni)                               \
          _acc[mi][ni] = __builtin_amdgcn_mfma_f32_16x16x32_bf16(                      \
              _a[mi], bfrag[kk][ni], _acc[mi][ni], 0, 0, 0);                           \
    }                                                                                  \
    /* pack acc -> zt (flipped bf16 pairs, [col][row/2], stride 17) */                 \
    _Pragma("unroll") for (int ni = 0; ni < 4; ++ni) {                                 \
      const int _col = w * 64 + ni * 16 + l15;                                         \
      const int _cb  = _col * 17 + l4 * 2;                                             \
      _Pragma("unroll") for (int mi = 0; mi < 2; ++mi)                                 \
        _Pragma("unroll") for (int p = 0; p < 2; ++p) {                                \
          unsigned _tpk = pk2(_acc[mi][ni][2 * p], _acc[mi][ni][2 * p + 1]);           \
          unsigned _mf = 0x80008000u + ((_tpk >> 15) & 0x00010001u) * 0x7FFFu;         \
          zt[_cb + mi * 8 + p] = _tpk ^ _mf;                                           \
        }                                                                              \
    }                                                                                  \
    LBAR();                                                                            \
    /* P2a: consume buffer (tile TT+G) -> lx; issued a full iteration ago */           \
    if (CAM) {                                                                         \
      uint2 _o0 = { pk2(CA0.x, CA0.y), pk2(CA0.z, CA0.w) };                            \
      uint2 _o1 = { pk2(CA1.x, CA1.y), pk2(CA1.z, CA1.w) };                            \
      uint2 _o2 = { pk2(CA2.x, CA2.y), pk2(CA2.z, CA2.w) };                            \
      uint2 _o3 = { pk2(CA3.x, CA3.y), pk2(CA3.z, CA3.w) };                            \
      unsigned short* _dst = &lx[row8 * 136 + s8 * 16];                                \
      *reinterpret_cast<uint2*>(_dst + 0)  = _o0;                                      \
      *reinterpret_cast<uint2*>(_dst + 4)  = _o1;                                      \
      *reinterpret_cast<uint2*>(_dst + 8)  = _o2;                                      \
      *reinterpret_cast<uint2*>(_dst + 12) = _o3;                                      \
      if (tid < 32) lvid[PCUR ^ 1][tid] = CAV;                                         \
    }                                                                                  \
    __builtin_amdgcn_sched_barrier(0);                                                 \
    /* P2b: walk zt: 1 thread/col, 32 rows; stores fire-and-forget */                  \
    {                                                                                  \
      const int _colw = tid;                                                           \
      const unsigned* _zc = &zt[_colw * 17];                                           \
      unsigned _curm = 0;                                                              \
      bool _first = true;                                                              \
      _Pragma("unroll") for (int p = 0; p < 16; ++p) {                                 \
        const unsigned _pr = _zc[p];                                                   \
        _Pragma("unroll") for (int j = 0; j < 2; ++j) {                                \
          const unsigned _val = j ? (_pr >> 16) : (_pr & 0xFFFFu);                     \
          _curm = _val > _curm ? _val : _curm;                                         \
          const int _row = p * 2 + j;                                                  \
          if ((_emask >> _row) & 1) {                                                  \
            const int _v = lvid[PCUR][_row];                                           \
            const unsigned _enc = flip32_from16(_curm);                                \
            unsigned* _ad = zu + (size_t)_v * DMID + _colw;                            \
            if (_first || _row == 31) atomicMax(_ad, _enc);                            \
            else *_ad = _enc;                                                          \
            _curm = 0; _first = false;                                                 \
          }                                                                            \
        }                                                                              \
      }                                                                                \
    }                                                                                  \
    LBAR();                                                                            \
  }

__global__ __launch_bounds__(256) void k_gemm1_max(
    const float* __restrict__ x, const int* __restrict__ vid,
    const int* __restrict__ sorted, const float* __restrict__ W1,
    const float* __restrict__ b1, unsigned* __restrict__ zu, int ntiles) {
  __shared__ unsigned short lx[32 * 136];   // x tile bf16 (row-major)
  __shared__ unsigned zt[256 * 17];         // z tile, flipped bf16 pairs
  __shared__ int lvid[2][32];

  const int tid  = threadIdx.x;
  const int lane = tid & 63;
  const int w    = tid >> 6;       // 0..3 -> col slice w*64
  const int l15  = lane & 15;
  const int l4   = lane >> 4;
  const int r32  = lane & 31;
  const int row8 = tid >> 3;       // staging: 8 threads per row (32 rows)
  const int s8   = tid & 7;        // 16 floats each
  const int G    = gridDim.x;

  // W1 fragments + bias for this wave's 64 cols
  bf16x8 bfrag[4][4];
  float  bias[4];
#pragma unroll
  for (int ni = 0; ni < 4; ++ni) {
    const int col = w * 64 + ni * 16 + l15;
    bias[ni] = b1[col];
#pragma unroll
    for (int kk = 0; kk < 4; ++kk) {
      union { bf16x8 v; unsigned short u[8]; } tmp;
#pragma unroll
      for (int j = 0; j < 8; ++j)
        tmp.u[j] = b16(W1[(kk * 32 + l4 * 8 + j) * DMID + col]);
      bfrag[kk][ni] = tmp.v;
    }
  }

  const int t0 = blockIdx.x;
  if (t0 >= ntiles) return;

  // ---- prologue: stage tile t0 directly; issue A = gather(t0+G);
  //      idx pair = indices of tile t0+2G ----
  {
    if (tid < 32) lvid[0][tid] = vid[sorted[t0 * 32 + tid]];
    const int eid = sorted[t0 * 32 + row8];
    const float4* src =
        reinterpret_cast<const float4*>(x + (size_t)eid * DIN + s8 * 16);
#pragma unroll
    for (int i = 0; i < 4; ++i) {
      float4 v = src[i];
      uint2 o = { pk2(v.x, v.y), pk2(v.z, v.w) };
      *reinterpret_cast<uint2*>(&lx[row8 * 136 + s8 * 16 + i * 4]) = o;
    }
  }
  float4 a0, a1, a2, a3, b0, b1c, b2, b3;
  int vA = 0, vB = 0;
  bool mA = (t0 + G) < ntiles, mB = false;
  if (mA) {
    const int eidA = sorted[(t0 + G) * 32 + row8];
    const float4* src =
        reinterpret_cast<const float4*>(x + (size_t)eidA * DIN + s8 * 16);
    a0 = src[0]; a1 = src[1]; a2 = src[2]; a3 = src[3];
    if (tid < 32) vA = vid[sorted[(t0 + G) * 32 + tid]];
  }
  int eidI = 0, sidI = 0;
  if ((t0 + 2 * G) < ntiles) {
    eidI = sorted[(t0 + 2 * G) * 32 + row8];
    if (tid < 32) sidI = sorted[(t0 + 2 * G) * 32 + tid];
  }
  __syncthreads();   // full drain once, outside the steady loop

  int t = t0;
  while (t < ntiles) {
    K1_ITER(t, a0, a1, a2, a3, vA, mA, b0, b1c, b2, b3, vB, mB, 0);
    t += G;
    if (t >= ntiles) break;
    K1_ITER(t, b0, b1c, b2, b3, vB, mB, a0, a1, a2, a3, vA, mA, 1);
    t += G;
  }
}

// ---------------------------------------------------------------------------
// Kernel Y: Y = unflip(zu) @ W2b  (V x 128). Block 256, wave 2x2.
// ---------------------------------------------------------------------------
__global__ __launch_bounds__(256) void k_ymm(
    const unsigned* __restrict__ zu, const float* __restrict__ W2,
    float* __restrict__ Y, int ntiles) {
  extern __shared__ unsigned short sm[];
  unsigned short* w2bt = sm;               // [128][264]
  unsigned short* za   = sm + 128 * 264;   // [64][264]

  const int tid  = threadIdx.x;
  const int lane = tid & 63;
  const int w    = tid >> 6;
  const int wr   = w >> 1, wc = w & 1;
  const int l15  = lane & 15, l4 = lane >> 4;

  {
    const int n = tid & 127, kh = tid >> 7;
    for (int k = kh * 128; k < kh * 128 + 128; ++k)
      w2bt[n * 264 + k] = b16(W2[(size_t)(DIN + k) * DOUT + n]);
  }
  __syncthreads();

  for (int t = blockIdx.x; t < ntiles; t += gridDim.x) {
    {
      const int row = tid >> 2, q = tid & 3;
      const int v = t * 64 + row;
      unsigned short* dz = &za[row * 264 + q * 64];
      if (v < VNUM) {
        const uint4* sz = reinterpret_cast<const uint4*>(zu + (size_t)v * DMID + q * 64);
#pragma unroll
        for (int i = 0; i < 16; ++i) {
          uint4 m = sz[i];
          ushort4 o = { (unsigned short)(unflip_bits(m.x) >> 16),
                        (unsigned short)(unflip_bits(m.y) >> 16),
                        (unsigned short)(unflip_bits(m.z) >> 16),
                        (unsigned short)(unflip_bits(m.w) >> 16) };
          *reinterpret_cast<ushort4*>(dz + i * 4) = o;
        }
      } else {
        ushort4 zo = {0, 0, 0, 0};
#pragma unroll
        for (int i = 0; i < 16; ++i) *reinterpret_cast<ushort4*>(dz + i * 4) = zo;
      }
    }
    __syncthreads();

    f32x4 acc[2][4];
#pragma unroll
    for (int mi = 0; mi < 2; ++mi)
#pragma unroll
      for (int ni = 0; ni < 4; ++ni) acc[mi][ni] = (f32x4){0.f, 0.f, 0.f, 0.f};

#pragma unroll
    for (int kk = 0; kk < 8; ++kk) {
      bf16x8 a[2], b[4];
#pragma unroll
      for (int mi = 0; mi < 2; ++mi)
        a[mi] = *reinterpret_cast<const bf16x8*>(
            &za[(wr * 32 + mi * 16 + l15) * 264 + kk * 32 + l4 * 8]);
#pragma unroll
      for (int ni = 0; ni < 4; ++ni)
        b[ni] = *reinterpret_cast<const bf16x8*>(
            &w2bt[(wc * 64 + ni * 16 + l15) * 264 + kk * 32 + l4 * 8]);
#pragma unroll
      for (int mi = 0; mi < 2; ++mi)
#pragma unroll
        for (int ni = 0; ni < 4; ++ni)
          acc[mi][ni] = __builtin_amdgcn_mfma_f32_16x16x32_bf16(
              a[mi], b[ni], acc[mi][ni], 0, 0, 0);
    }

#pragma unroll
    for (int mi = 0; mi < 2; ++mi)
#pragma unroll
      for (int r = 0; r < 4; ++r) {
        const int v = t * 64 + wr * 32 + mi * 16 + l4 * 4 + r;
        if (v < VNUM) {
          float* o = Y + (size_t)v * DOUT + wc * 64 + l15;
#pragma unroll
          for (int ni = 0; ni < 4; ++ni) o[ni * 16] = acc[mi][ni][r];
        }
      }
    __syncthreads();
  }
}

// ---------------------------------------------------------------------------
// Kernel 2: out = x @ W2a + Y[vid]  (original edge order). Block 256, wave
// 2x2; Y[vid] gathers issued before MFMA; LDS-only barriers.
// NOTE: no min-waves hint (r5/r6 lesson) — yv grew the live set past where
// the old (256,3) cap was sized.
// ---------------------------------------------------------------------------
__global__ __launch_bounds__(256) void k_gemm2(
    const float* __restrict__ x, const int* __restrict__ vid,
    const float* __restrict__ W2, const float* __restrict__ Y,
    float* __restrict__ out, int ntiles) {
  __shared__ unsigned short w2at[128 * 136];
  __shared__ unsigned short lx[64 * 136];
  __shared__ int lvid[64];

  const int tid  = threadIdx.x;
  const int lane = tid & 63;
  const int w    = tid >> 6;
  const int wr   = w >> 1, wc = w & 1;
  const int l15  = lane & 15, l4 = lane >> 4;

  {
    const int n = tid & 127, kh = tid >> 7;
    for (int k = kh * 64; k < kh * 64 + 64; ++k)
      w2at[n * 136 + k] = b16(W2[(size_t)k * DOUT + n]);
  }
  __syncthreads();

  for (int t = blockIdx.x; t < ntiles; t += gridDim.x) {
    {
      const int row = tid >> 2, q = tid & 3;
      const float4* sx =
          reinterpret_cast<const float4*>(x + (size_t)(t * 64 + row) * DIN + q * 32);
#pragma unroll
      for (int i = 0; i < 8; ++i) {
        float4 v = sx[i];
        uint2 o = { pk2(v.x, v.y), pk2(v.z, v.w) };
        *reinterpret_cast<uint2*>(&lx[row * 136 + q * 32 + i * 4]) = o;
      }
      if (tid < 64) lvid[tid] = vid[t * 64 + tid];
    }
    LBAR();

    // ---- issue Y gathers (consumed after MFMA) ----
    float yv[2][4][4];  // [mi][r][ni]
#pragma unroll
    for (int mi = 0; mi < 2; ++mi)
#pragma unroll
      for (int r = 0; r < 4; ++r) {
        const int row = wr * 32 + mi * 16 + l4 * 4 + r;
        const float* Yr = Y + (size_t)lvid[row] * DOUT + wc * 64 + l15;
#pragma unroll
        for (int ni = 0; ni < 4; ++ni) yv[mi][r][ni] = Yr[ni * 16];
      }

    f32x4 acc[2][4];
#pragma unroll
    for (int mi = 0; mi < 2; ++mi)
#pragma unroll
      for (int ni = 0; ni < 4; ++ni) acc[mi][ni] = (f32x4){0.f, 0.f, 0.f, 0.f};

#pragma unroll
    for (int kk = 0; kk < 4; ++kk) {
      bf16x8 a[2], b[4];
#pragma unroll
      for (int mi = 0; mi < 2; ++mi)
        a[mi] = *reinterpret_cast<const bf16x8*>(
            &lx[(wr * 32 + mi * 16 + l15) * 136 + kk * 32 + l4 * 8]);
#pragma unroll
      for (int ni = 0; ni < 4; ++ni)
        b[ni] = *reinterpret_cast<const bf16x8*>(
            &w2at[(wc * 64 + ni * 16 + l15) * 136 + kk * 32 + l4 * 8]);
#pragma unroll
      for (int mi = 0; mi < 2; ++mi)
#pragma unroll
        for (int ni = 0; ni < 4; ++ni)
          acc[mi][ni] = __builtin_amdgcn_mfma_f32_16x16x32_bf16(
              a[mi], b[ni], acc[mi][ni], 0, 0, 0);
    }

#pragma unroll
    for (int mi = 0; mi < 2; ++mi)
#pragma unroll
      for (int r = 0; r < 4; ++r) {
        const int row = wr * 32 + mi * 16 + l4 * 4 + r;
        float* o = out + (size_t)(t * 64 + row) * DOUT + wc * 64 + l15;
#pragma unroll
        for (int ni = 0; ni < 4; ++ni) o[ni * 16] = acc[mi][ni][r] + yv[mi][r][ni];
      }
    LBAR();
  }
}

// ---------------------------------------------------------------------------
extern "C" void kernel_launch(void* const* d_in, const int* in_sizes, int n_in,
                              void* d_out, int out_size, void* d_ws, size_t ws_size,
                              hipStream_t stream) {
  const float* x   = (const float*)d_in[0];
  const int*   vid = (const int*)d_in[1];
  const float* W1  = (const float*)d_in[2];
  const float* b1  = (const float*)d_in[3];
  const float* W2  = (const float*)d_in[4];
  float* out = (float*)d_out;

  const int E = in_sizes[1];          // 800000
  const int ntiles32 = E / 32;        // 25000
  const int ntiles64 = E / 64;        // 12500
  const int ntY = (VNUM + 63) / 64;   // 782
  const int nb = (VNUM + 255) / 256;  // 196 scan blocks

  char* ws = (char*)d_ws;
  size_t off = 0;
  unsigned* zu = (unsigned*)(ws + off); off += (size_t)VNUM * DMID * 4;
  int* cnt     = (int*)(ws + off);      off += (size_t)VNUM * 4;
  int* sorted  = (int*)(ws + off);      off += (size_t)E * 4;
  float* Y     = (float*)(ws + off);    off += (size_t)VNUM * DOUT * 4;
  int* bsum    = (int*)(ws + off);      off += 4096;

  const int n16 = (int)(((size_t)VNUM * DMID * 4 + VNUM * 4) / 16);
  k_zero<<<2048, 256, 0, stream>>>((uint4*)zu, n16);

  k_hist<<<(E + 255) / 256, 256, 0, stream>>>(vid, cnt, E);
  k_scan_red<<<nb, 256, 0, stream>>>(cnt, bsum, VNUM);
  k_scan_top<<<1, 256, 0, stream>>>(bsum, nb);
  k_scan_fix<<<nb, 256, 0, stream>>>(cnt, bsum, VNUM);
  k_scatter<<<(E + 255) / 256, 256, 0, stream>>>(vid, cnt, sorted, E);

  // persistent grid; residency set by VGPR (expect ~3 blocks/CU at ~150 VGPR)
  k_gemm1_max<<<1024, 256, 0, stream>>>(x, vid, sorted, W1, b1, zu, ntiles32);

  const int smY = (128 * 264 + 64 * 264) * sizeof(unsigned short);
  hipFuncSetAttribute((const void*)k_ymm,
                      hipFuncAttributeMaxDynamicSharedMemorySize, smY);
  k_ymm<<<782, 256, smY, stream>>>(zu, W2, Y, ntY);

  k_gemm2<<<768, 256, 0, stream>>>(x, vid, W2, Y, out, ntiles64);
}